// Round 5
// baseline (281.017 us; speedup 1.0000x reference)
//
#include <hip/hip_runtime.h>
#include <math.h>

typedef __bf16 bf16;
typedef __attribute__((ext_vector_type(4))) __bf16 bf16x4;
typedef __attribute__((ext_vector_type(8))) __bf16 bf16x8;
typedef __attribute__((ext_vector_type(4))) float f32x4;
typedef __attribute__((ext_vector_type(2))) float f32x2;

#define MFMA16(a, b, c) __builtin_amdgcn_mfma_f32_16x16x32_bf16(a, b, c, 0, 0, 0)

#define SN 1312           // WT row stride in f32 (1282 used, padded)
#define NTQ 4096

// ---------------------------------------------------------------------------
// k_tw: transpose weights into WT[i=256][n]:
//   n in [0,1024)    = slow_W rows 0..1023  (a1|a2|s1|s2)
//   n in [1024,1280) = w0 rows 0..255
//   n = 1280 / 1281  = slow_W rows 1024 (sa) / 1025 (ss)
// ---------------------------------------------------------------------------
__global__ __launch_bounds__(256) void k_tw(const float* __restrict__ sw,
                                            const float* __restrict__ w0,
                                            float* __restrict__ WT) {
    const int n = blockIdx.x;
    const int i = threadIdx.x;
    const float* src;
    if (n < 1024)      src = sw + (size_t)n * 256;
    else if (n < 1280) src = w0 + (size_t)(n - 1024) * 256;
    else               src = sw + (size_t)(1024 + (n - 1280)) * 256;
    WT[(size_t)i * SN + n] = src[i];
}

// ---------------------------------------------------------------------------
// k_prep: fused wu GEMM (fp32 VALU) + layouts, grid (64, 6), 256 thr (4 waves).
//  y=0: cols 0..255    -> A1B[kt][o][k'] bf16 (tile-packed) ; also writes Xg
//  y=1: cols 256..511  -> A2g[jb][i] bf16
//  y=2: cols 512..767  -> S1B
//  y=3: cols 768..1023 -> S2g
//  y=4: w0 cols        -> out (f32 base, no bias)
//  y=5: gates          -> sag/ssg (fp32 sigmoid)
// Per block: 64 rows; wave w owns rows r0+16w..+16 (private LDS stage, no barrier).
// ---------------------------------------------------------------------------
__global__ __launch_bounds__(256) void k_prep(const float* __restrict__ x,
                                              const float* __restrict__ WT,
                                              const float* __restrict__ sb,
                                              bf16* __restrict__ A1B,
                                              bf16* __restrict__ A2g,
                                              bf16* __restrict__ S1B,
                                              bf16* __restrict__ S2g,
                                              bf16* __restrict__ Xg,
                                              float* __restrict__ out,
                                              float* __restrict__ sag,
                                              float* __restrict__ ssg) {
    const int y  = blockIdx.y;
    const int r0 = blockIdx.x * 64;
    const int t  = threadIdx.x;

    if (y == 5) {   // gates: 64 rows x 2 gates
        if (t < 128) {
            const int row = r0 + (t >> 1);
            const int gi  = t & 1;
            const float4* xr = (const float4*)(x + (size_t)row * 256);
            float a = 0.f;
            for (int i4 = 0; i4 < 64; ++i4) {
                const float4 xv = xr[i4];
                a = fmaf(WT[(size_t)(i4 * 4 + 0) * SN + 1280 + gi], xv.x, a);
                a = fmaf(WT[(size_t)(i4 * 4 + 1) * SN + 1280 + gi], xv.y, a);
                a = fmaf(WT[(size_t)(i4 * 4 + 2) * SN + 1280 + gi], xv.z, a);
                a = fmaf(WT[(size_t)(i4 * 4 + 3) * SN + 1280 + gi], xv.w, a);
            }
            const float z = a + sb[1024 + gi];
            (gi ? ssg : sag)[row] = 1.0f / (1.0f + expf(-z));
        }
        return;
    }

    const int w  = t >> 6, l = t & 63;
    const int rw = r0 + w * 16;

    __shared__ __align__(16) float xld[4][16][256];
    // stage this wave's 16 x-rows (wave-private -> no barrier needed)
#pragma unroll
    for (int rr = 0; rr < 16; ++rr) {
        const float4 v = *(const float4*)(x + (size_t)(rw + rr) * 256 + l * 4);
        *(float4*)&xld[w][rr][l * 4] = v;
        if (y == 0) {
            bf16x4 o;
            o[0] = (bf16)v.x; o[1] = (bf16)v.y; o[2] = (bf16)v.z; o[3] = (bf16)v.w;
            *(bf16x4*)(Xg + (size_t)(rw + rr) * 256 + l * 4) = o;
        }
    }

    float acc[4][16];
#pragma unroll
    for (int c = 0; c < 4; ++c)
#pragma unroll
        for (int rr = 0; rr < 16; ++rr) acc[c][rr] = 0.f;

    const float* wp = WT + (size_t)y * 256 + (size_t)l * 4;
    for (int i4 = 0; i4 < 64; ++i4) {
        float4 wv[4];
#pragma unroll
        for (int d = 0; d < 4; ++d)
            wv[d] = *(const float4*)(wp + (size_t)(i4 * 4 + d) * SN);
#pragma unroll
        for (int rr = 0; rr < 16; ++rr) {
            const float4 xv = *(const float4*)&xld[w][rr][i4 * 4];
#pragma unroll
            for (int c = 0; c < 4; ++c) {
                acc[c][rr] = fmaf(wv[0][c], xv.x, acc[c][rr]);
                acc[c][rr] = fmaf(wv[1][c], xv.y, acc[c][rr]);
                acc[c][rr] = fmaf(wv[2][c], xv.z, acc[c][rr]);
                acc[c][rr] = fmaf(wv[3][c], xv.w, acc[c][rr]);
            }
        }
    }

    if (y == 4) {   // base GEMM -> out (f32, no bias)
#pragma unroll
        for (int rr = 0; rr < 16; ++rr) {
            float4 v;
            v.x = acc[0][rr]; v.y = acc[1][rr]; v.z = acc[2][rr]; v.w = acc[3][rr];
            *(float4*)(out + (size_t)(rw + rr) * 256 + l * 4) = v;
        }
        return;
    }

    // slow bias
    float bv[4];
#pragma unroll
    for (int c = 0; c < 4; ++c) bv[c] = sb[y * 256 + l * 4 + c];

    if (y == 0 || y == 2) {   // tile-packed transposed: [kt][o][k']
        bf16* dst = (y == 0 ? A1B : S1B) + (size_t)(r0 >> 6) * 16384;
#pragma unroll
        for (int c = 0; c < 4; ++c) {
            bf16x8 p0, p1;
#pragma unroll
            for (int rr = 0; rr < 8; ++rr) {
                p0[rr] = (bf16)(acc[c][rr] + bv[c]);
                p1[rr] = (bf16)(acc[c][rr + 8] + bv[c]);
            }
            bf16* dp = dst + (size_t)(l * 4 + c) * 64 + w * 16;
            *(bf16x8*)dp       = p0;
            *(bf16x8*)(dp + 8) = p1;
        }
    } else {                   // row-major: [jb][i]
        bf16* dst = (y == 1 ? A2g : S2g);
#pragma unroll
        for (int rr = 0; rr < 16; ++rr) {
            bf16x4 p;
#pragma unroll
            for (int c = 0; c < 4; ++c) p[c] = (bf16)(acc[c][rr] + bv[c]);
            *(bf16x4*)(dst + (size_t)(rw + rr) * 256 + l * 4) = p;
        }
    }
}

// ---------------------------------------------------------------------------
// k_attn: wave-autonomous blockwise-causal linear attention. No barriers.
// Work unit u (0..2175) = (qt 16-row Q-tile, s kt-segment of <=4 kt-tiles).
// Unit count per qt = qt/16+1 (group g=qt/16 has 16 qt x (g+1) units).
// Per kt-iter: S(16x128, K=256) MFMA -> private LDS f32 transpose ->
// gate via 4 ds_bpermute (e-invariant) -> out(16x256, K'=128) MFMA.
// ---------------------------------------------------------------------------
__global__ __launch_bounds__(256, 2) void k_attn(const bf16* __restrict__ A2g,
                                                 const bf16* __restrict__ S2g,
                                                 const bf16* __restrict__ A1B,
                                                 const bf16* __restrict__ S1B,
                                                 const bf16* __restrict__ Xg,
                                                 const float* __restrict__ sag,
                                                 const float* __restrict__ ssg,
                                                 float* __restrict__ part) {
    const int t = threadIdx.x, l = t & 63, w = t >> 6;
    const int u = blockIdx.x * 4 + w;

    int g = 0;
    while (8 * (g + 1) * (g + 2) <= u) ++g;       // <=15 iters, wave-uniform
    const int rem = u - 8 * g * (g + 1);
    const int den = g + 1;
    const int qi  = rem / den;
    const int s   = rem - qi * den;
    const int qt  = 16 * g + qi;
    const int tq0 = qt * 16;
    const int nkt = (qt >> 2) + 1;
    const int kt0 = s * 4;
    const int ktE = (kt0 + 4 < nkt) ? kt0 + 4 : nkt;

    const int lr = l & 15, lc = l >> 4;
    const int jrow = 2 * qt + (lr >> 3);
    const int bsel = (lc * 8 + (lr & 7)) * 4;      // bpermute byte addr (par 0)

    __shared__ __align__(16) float PTall[4][128 * 18];
    float* PT = PTall[w];

    bf16x8 xa[8];
#pragma unroll
    for (int kk = 0; kk < 8; ++kk)
        xa[kk] = *(const bf16x8*)(Xg + (size_t)(tq0 + lr) * 256 + kk * 32 + lc * 8);

    f32x4 acco[16];
#pragma unroll
    for (int ni = 0; ni < 16; ++ni) acco[ni] = (f32x4){0.f, 0.f, 0.f, 0.f};

    for (int kt = kt0; kt < ktE; ++kt) {
        const int TK0 = kt * 64;
        const float sgA = sag[TK0 + l];
        const float sgS = ssg[TK0 + l];

        // ---- S phase: 16 rows x 128 score-cols, K=256 ----
        f32x4 accs[2][4];
#pragma unroll
        for (int p = 0; p < 2; ++p)
#pragma unroll
            for (int ni = 0; ni < 4; ++ni) accs[p][ni] = (f32x4){0.f, 0.f, 0.f, 0.f};
#pragma unroll
        for (int kk = 0; kk < 8; ++kk) {
#pragma unroll
            for (int ni = 0; ni < 4; ++ni) {
                const bf16x8 ba = *(const bf16x8*)(A2g +
                    (size_t)(TK0 + ni * 16 + lr) * 256 + kk * 32 + lc * 8);
                accs[0][ni] = MFMA16(xa[kk], ba, accs[0][ni]);
            }
#pragma unroll
            for (int ni = 0; ni < 4; ++ni) {
                const bf16x8 bs = *(const bf16x8*)(S2g +
                    (size_t)(TK0 + ni * 16 + lr) * 256 + kk * 32 + lc * 8);
                accs[1][ni] = MFMA16(xa[kk], bs, accs[1][ni]);
            }
        }

        // ---- transpose S into private LDS (f32, stride 18, b64 writes) ----
#pragma unroll
        for (int p = 0; p < 2; ++p)
#pragma unroll
            for (int ni = 0; ni < 4; ++ni) {
                const int col = p * 64 + ni * 16 + lr;
                f32x2 lo, hi;
                lo[0] = accs[p][ni][0]; lo[1] = accs[p][ni][1];
                hi[0] = accs[p][ni][2]; hi[1] = accs[p][ni][3];
                *(f32x2*)&PT[col * 18 + lc * 4]     = lo;
                *(f32x2*)&PT[col * 18 + lc * 4 + 2] = hi;
            }

        // ---- gates: e-invariant, one value per (kk2) via bpermute ----
        int giA0 = __builtin_amdgcn_ds_bpermute(bsel,       __float_as_int(sgA));
        int giA1 = __builtin_amdgcn_ds_bpermute(bsel + 128, __float_as_int(sgA));
        int giS0 = __builtin_amdgcn_ds_bpermute(bsel,       __float_as_int(sgS));
        int giS1 = __builtin_amdgcn_ds_bpermute(bsel + 128, __float_as_int(sgS));
        const float gk[4] = { __int_as_float(giA0),  __int_as_float(giA1),
                             -__int_as_float(giS0), -__int_as_float(giS1)};

        // ---- out phase: gate+mask+bf16 at LDS read-back, 16x256 K'=128 ----
#pragma unroll
        for (int kk2 = 0; kk2 < 4; ++kk2) {
            float gg = gk[kk2];
            const int tstep = kt * 8 + (kk2 & 1) * 4 + lc;   // key j-step (FIXED)
            if (tstep > jrow) gg = 0.f;            // causal mask (e-invariant)
            const int colb = kk2 * 32 + lc * 8;
            bf16x8 af;
#pragma unroll
            for (int e = 0; e < 8; ++e)
                af[e] = (bf16)(gg * PT[(colb + e) * 18 + lr]);
            const bf16* tp = ((kk2 < 2) ? A1B : S1B) + (size_t)kt * 16384 +
                             (kk2 & 1) * 32 + lc * 8;
#pragma unroll
            for (int ni = 0; ni < 16; ++ni) {
                const bf16x8 bfg = *(const bf16x8*)(tp + (size_t)(ni * 16 + lr) * 64);
                acco[ni] = MFMA16(af, bfg, acco[ni]);
            }
        }
    }

    // ---- partial write ----
    float* dp = part + (size_t)u * 4096;
#pragma unroll
    for (int ni = 0; ni < 16; ++ni)
#pragma unroll
        for (int v = 0; v < 4; ++v)
            dp[(lc * 4 + v) * 256 + ni * 16 + lr] = acco[ni][v];
}

// ---------------------------------------------------------------------------
// k_reduce: out += ragged sum of partials (closed-form unit offsets)
// ---------------------------------------------------------------------------
__global__ __launch_bounds__(256) void k_reduce(const float* __restrict__ part,
                                                float* __restrict__ out) {
    const int idx = blockIdx.x * 256 + threadIdx.x;  // f32x4 units, 262144 total
    const int row = idx >> 6;
    const int qt  = row >> 4;
    const int g   = qt >> 4;
    const int cnt = g + 1;
    const int us  = 8 * g * (g + 1) + (qt & 15) * cnt;
    f32x4 acc = ((const f32x4*)out)[idx];
    const f32x4* pp = (const f32x4*)part + (size_t)us * 1024 +
                      (row & 15) * 64 + (idx & 63);
    for (int s2 = 0; s2 < cnt; ++s2) acc += pp[(size_t)s2 * 1024];
    ((f32x4*)out)[idx] = acc;
}

// ---------------------------------------------------------------------------
extern "C" void kernel_launch(void* const* d_in, const int* in_sizes, int n_in,
                              void* d_out, int out_size, void* d_ws, size_t ws_size,
                              hipStream_t stream) {
    const float* x  = (const float*)d_in[0];
    const float* sw = (const float*)d_in[1];
    const float* sb = (const float*)d_in[2];
    const float* w0 = (const float*)d_in[3];
    float* out = (float*)d_out;

    float* WT  = (float*)d_ws;                       // 256*1312 f32
    bf16* A1B  = (bf16*)(WT + (size_t)256 * SN);     // 1M bf16 each
    bf16* S1B  = A1B + (size_t)1048576;
    bf16* A2g  = S1B + (size_t)1048576;
    bf16* S2g  = A2g + (size_t)1048576;
    bf16* Xg   = S2g + (size_t)1048576;
    float* sag = (float*)(Xg + (size_t)1048576);
    float* ssg = sag + NTQ;
    float* part = ssg + NTQ;                         // 2176 * 4096 f32

    k_tw<<<1282, 256, 0, stream>>>(sw, w0, WT);
    dim3 gp(64, 6);
    k_prep<<<gp, 256, 0, stream>>>(x, WT, sb, A1B, A2g, S1B, S2g, Xg, out, sag, ssg);
    k_attn<<<544, 256, 0, stream>>>(A2g, S2g, A1B, S1B, Xg, sag, ssg, part);
    k_reduce<<<1024, 256, 0, stream>>>(part, out);
}

// Round 6
// 202.385 us; speedup vs baseline: 1.3885x; 1.3885x over previous
//
#include <hip/hip_runtime.h>
#include <math.h>

typedef __bf16 bf16;
typedef __attribute__((ext_vector_type(4))) __bf16 bf16x4;
typedef __attribute__((ext_vector_type(8))) __bf16 bf16x8;
typedef __attribute__((ext_vector_type(4))) float f32x4;

#define MFMA16(a, b, c) __builtin_amdgcn_mfma_f32_16x16x32_bf16(a, b, c, 0, 0, 0)
#define NTQ 4096

// ---------------------------------------------------------------------------
// k_xb: x (f32 row-major 4096x256) -> Xb (bf16 row-major)
// ---------------------------------------------------------------------------
__global__ __launch_bounds__(256) void k_xb(const float* __restrict__ x,
                                            bf16* __restrict__ Xb) {
    const int idx = blockIdx.x * 256 + threadIdx.x;   // f32x4 units, 262144
    const float4 v = ((const float4*)x)[idx];
    bf16x4 o;
    o[0] = (bf16)v.x; o[1] = (bf16)v.y; o[2] = (bf16)v.z; o[3] = (bf16)v.w;
    ((bf16x4*)Xb)[idx] = o;
}

// ---------------------------------------------------------------------------
// k_tw: weights -> WB, pre-swizzled MFMA B-fragment layout (bf16).
// WB[((nb16*8 + kk)*64 + l)*8 + e] = W[n = nb16*16 + (l&15)][i = kk*32 + (l>>4)*8 + e]
//   n in [0,1024): slow_W rows (a1|a2|s1|s2); [1024,1280): w0; 1280/1281: gates;
//   n >= 1282: zero padding. nb16 in [0,84).
// ---------------------------------------------------------------------------
__global__ __launch_bounds__(256) void k_tw(const float* __restrict__ sw,
                                            const float* __restrict__ w0,
                                            bf16* __restrict__ WB) {
    const int nb = blockIdx.x;                 // 0..83
    const int t = threadIdx.x, l = t & 63, kg = t >> 6;
    const int n = nb * 16 + (l & 15);
#pragma unroll
    for (int pass = 0; pass < 2; ++pass) {
        const int kk = kg + pass * 4;
        const int i0 = kk * 32 + (l >> 4) * 8;
        bf16x8 o;
        if (n < 1282) {
            const float* src = (n < 1024) ? (sw + (size_t)n * 256)
                             : (n < 1280) ? (w0 + (size_t)(n - 1024) * 256)
                                          : (sw + (size_t)(1024 + (n - 1280)) * 256);
#pragma unroll
            for (int e = 0; e < 8; ++e) o[e] = (bf16)src[i0 + e];
        } else {
#pragma unroll
            for (int e = 0; e < 8; ++e) o[e] = (bf16)0.0f;
        }
        *(bf16x8*)(WB + ((size_t)(nb * 8 + kk) * 64 + l) * 8) = o;
    }
}

// ---------------------------------------------------------------------------
// k_prep: MFMA GEMM  C[4096 x 1282] = Xb @ W^T  (+bias / sigmoid / layouts).
// grid (64 mb, 21 nb64), 256 thr / 4 waves; wave w: rows rw=mb*64+w*16, cols n0..n0+63.
//  nb 0..3   -> A1B[kt][o][k'] (tile-packed bf16, +bias)
//  nb 4..7   -> A2g[jb][i]     (row-major bf16, +bias)
//  nb 8..11  -> S1B            (tile-packed)
//  nb 12..15 -> S2g            (row-major)
//  nb 16..19 -> out f32 base (W0 @ x, no bias)
//  nb 20     -> gates (sigmoid) -> sag/ssg
// ---------------------------------------------------------------------------
__global__ __launch_bounds__(256) void k_prep(const bf16* __restrict__ Xb,
                                              const bf16* __restrict__ WB,
                                              const float* __restrict__ sb,
                                              bf16* __restrict__ A1B,
                                              bf16* __restrict__ A2g,
                                              bf16* __restrict__ S1B,
                                              bf16* __restrict__ S2g,
                                              float* __restrict__ out,
                                              float* __restrict__ sag,
                                              float* __restrict__ ssg) {
    const int mb = blockIdx.x, nb = blockIdx.y;
    const int t = threadIdx.x, l = t & 63, w = t >> 6;
    const int lr = l & 15, lc = l >> 4;
    const int rw = mb * 64 + w * 16;
    const int n0 = nb * 64;

    f32x4 acc[4];
#pragma unroll
    for (int ni = 0; ni < 4; ++ni) acc[ni] = (f32x4){0.f, 0.f, 0.f, 0.f};

#pragma unroll
    for (int kk = 0; kk < 8; ++kk) {
        const bf16x8 a = *(const bf16x8*)(Xb + (size_t)(rw + lr) * 256 + kk * 32 + lc * 8);
#pragma unroll
        for (int ni = 0; ni < 4; ++ni) {
            const bf16x8 b = *(const bf16x8*)(WB +
                ((size_t)((nb * 4 + ni) * 8 + kk) * 64 + l) * 8);
            acc[ni] = MFMA16(a, b, acc[ni]);
        }
    }

    if (nb == 20) {   // gates: valid cols are n = 1280 + lr (lr<2), ni==0
        if (lr < 2) {
            const float bz = sb[1024 + lr];
            float* dst = lr ? ssg : sag;
#pragma unroll
            for (int v = 0; v < 4; ++v) {
                const float z = acc[0][v] + bz;
                dst[rw + lc * 4 + v] = 1.0f / (1.0f + expf(-z));
            }
        }
        return;
    }

    const int typ = nb >> 2;
    if (typ == 4) {   // base out (f32, no bias)
#pragma unroll
        for (int ni = 0; ni < 4; ++ni) {
            const int o = (n0 - 1024) + ni * 16 + lr;
#pragma unroll
            for (int v = 0; v < 4; ++v)
                out[(size_t)(rw + lc * 4 + v) * 256 + o] = acc[ni][v];
        }
        return;
    }

    if (typ == 0 || typ == 2) {   // tile-packed [kt=mb][o][k']
        bf16* dst = (typ == 0 ? A1B : S1B) + (size_t)mb * 16384;
        const int ob = n0 - (typ == 0 ? 0 : 512);
#pragma unroll
        for (int ni = 0; ni < 4; ++ni) {
            const int o = ob + ni * 16 + lr;
            const float bz = sb[n0 + ni * 16 + lr];
            bf16x4 p;
#pragma unroll
            for (int v = 0; v < 4; ++v) p[v] = (bf16)(acc[ni][v] + bz);
            *(bf16x4*)(dst + (size_t)o * 64 + w * 16 + lc * 4) = p;
        }
    } else {                      // row-major [jb][i]
        bf16* dst = (typ == 1 ? A2g : S2g);
        const int ib = n0 - (typ == 1 ? 256 : 768);
#pragma unroll
        for (int ni = 0; ni < 4; ++ni) {
            const int i = ib + ni * 16 + lr;
            const float bz = sb[n0 + ni * 16 + lr];
#pragma unroll
            for (int v = 0; v < 4; ++v)
                dst[(size_t)(rw + lc * 4 + v) * 256 + i] = (bf16)(acc[ni][v] + bz);
        }
    }
}

// ---------------------------------------------------------------------------
// k_attn: blockwise-causal linear attention (r3 structure + symmetric merge).
// Block = (q-tile 64 rows, seg of <=SEGT kt-tiles), 8 waves (ih = K-half,
// sub = 32 score-cols). Per kt: S-phase MFMA (K-half per wave) ->
// each half ships its OTHER half's rows to PT -> barrier -> both halves
// merge+gate+mask+cvt their OWN rows into PB (all 8 waves busy) -> barrier ->
// out-phase MFMA (wave owns o-cols w*32..+32). Partials per seg; no atomics.
// ---------------------------------------------------------------------------
__global__ __launch_bounds__(512, 2) void k_attn(const bf16* __restrict__ A2g,
                                                 const bf16* __restrict__ S2g,
                                                 const bf16* __restrict__ A1B,
                                                 const bf16* __restrict__ S1B,
                                                 const bf16* __restrict__ Xb,
                                                 const float* __restrict__ sag,
                                                 const float* __restrict__ ssg,
                                                 float* __restrict__ part,
                                                 int SEGT) {
    const int q = blockIdx.x, seg = blockIdx.y;
    int kt = seg * SEGT;
    const int ktEnd = min(kt + SEGT, q + 1);
    if (kt >= ktEnd) return;

    const int tid = threadIdx.x, l = tid & 63, w = tid >> 6;
    const int lr = l & 15, lc = l >> 4;
    const int ih = w >> 2, sub = w & 3;
    const int tq0 = q * 64;

    __shared__ __align__(16) float PTa[128 * 34];   // rows 32..63 (written by ih0)
    __shared__ __align__(16) float PTb[128 * 34];   // rows 0..31  (written by ih1)
    __shared__ __align__(16) bf16 PB[64][136];
    __shared__ float ga[64], gs[64];

    // persistent X fragments (this wave's K-half)
    bf16x8 xa[4][4];
#pragma unroll
    for (int mi = 0; mi < 4; ++mi)
#pragma unroll
        for (int kk = 0; kk < 4; ++kk)
            xa[mi][kk] = *(const bf16x8*)(Xb + (size_t)(tq0 + mi * 16 + lr) * 256 +
                                          ih * 128 + kk * 32 + lc * 8);

    f32x4 acco[4][2];
#pragma unroll
    for (int mi = 0; mi < 4; ++mi)
#pragma unroll
        for (int ni = 0; ni < 2; ++ni) acco[mi][ni] = (f32x4){0.f, 0.f, 0.f, 0.f};

    const bf16* Bsrc = (sub < 2) ? A2g : S2g;
    const float sgn  = (sub < 2) ? 1.f : -1.f;

    for (; kt < ktEnd; ++kt) {
        const int TK0 = kt * 64;
        if (tid < 64) ga[tid] = sag[TK0 + tid];
        else if (tid < 128) gs[tid - 64] = ssg[TK0 + tid - 64];

        // ---- S phase (K-half per wave) ----
        f32x4 accs[4][2];
#pragma unroll
        for (int mi = 0; mi < 4; ++mi)
#pragma unroll
            for (int ni = 0; ni < 2; ++ni) accs[mi][ni] = (f32x4){0.f, 0.f, 0.f, 0.f};
#pragma unroll
        for (int kk = 0; kk < 4; ++kk) {
#pragma unroll
            for (int ni = 0; ni < 2; ++ni) {
                const bf16x8 bfg = *(const bf16x8*)(Bsrc +
                    (size_t)(TK0 + (sub & 1) * 32 + ni * 16 + lr) * 256 +
                    ih * 128 + kk * 32 + lc * 8);
#pragma unroll
                for (int mi = 0; mi < 4; ++mi)
                    accs[mi][ni] = MFMA16(xa[mi][kk], bfg, accs[mi][ni]);
            }
        }

        // ---- ship the OTHER half's rows to PT ----
        float* PTw = ih ? PTb : PTa;
        const int mw = 2 - 2 * ih;             // ih0 -> mi 2,3 ; ih1 -> mi 0,1
#pragma unroll
        for (int mk = 0; mk < 2; ++mk)
#pragma unroll
            for (int ni = 0; ni < 2; ++ni) {
                const int cL = sub * 32 + ni * 16 + lr;
                *(f32x4*)&PTw[cL * 34 + mk * 16 + lc * 4] = accs[mw + mk][ni];
            }
        __syncthreads();   // B1: PT + gates visible

        // ---- merge OWN half's rows -> PB (all 8 waves busy) ----
        const float* PTr = ih ? PTa : PTb;
        const int mo = 2 * ih;
#pragma unroll
        for (int mk = 0; mk < 2; ++mk)
#pragma unroll
            for (int ni = 0; ni < 2; ++ni) {
                const int cL  = sub * 32 + ni * 16 + lr;
                const int tkL = cL & 63;
                const f32x4 oth = *(const f32x4*)&PTr[cL * 34 + mk * 16 + lc * 4];
#pragma unroll
                for (int v = 0; v < 4; ++v) {
                    const int row = ih * 32 + mk * 16 + lc * 4 + v;
                    const float gg = (sub < 2 ? ga : gs)[(tkL & 56) + (row & 7)];
                    float p = sgn * gg * (accs[mo + mk][ni][v] + oth[v]);
                    const int ks = kt * 8 + (tkL >> 3);
                    const int js = q * 8 + (row >> 3);
                    if (ks > js) p = 0.f;          // causal
                    PB[row][cL] = (bf16)p;
                }
            }
        __syncthreads();   // B2: PB visible

        // ---- out phase: o-cols [w*32, w*32+32), K' = 128 ----
#pragma unroll
        for (int kk2 = 0; kk2 < 4; ++kk2) {
            const bf16* Tsrc = (kk2 < 2) ? A1B : S1B;
            bf16x8 af[4];
#pragma unroll
            for (int mi = 0; mi < 4; ++mi)
                af[mi] = *(const bf16x8*)&PB[mi * 16 + lr][kk2 * 32 + lc * 8];
#pragma unroll
            for (int nio = 0; nio < 2; ++nio) {
                const bf16x8 bfg = *(const bf16x8*)(Tsrc + (size_t)kt * 16384 +
                    (size_t)(w * 32 + nio * 16 + lr) * 64 + (kk2 & 1) * 32 + lc * 8);
#pragma unroll
                for (int mi = 0; mi < 4; ++mi)
                    acco[mi][nio] = MFMA16(af[mi], bfg, acco[mi][nio]);
            }
        }
    }

    // ---- per-segment partial write (no atomics) ----
    float* dst = part + (size_t)seg * ((size_t)NTQ * 256);
#pragma unroll
    for (int mi = 0; mi < 4; ++mi)
#pragma unroll
        for (int nio = 0; nio < 2; ++nio)
#pragma unroll
            for (int v = 0; v < 4; ++v)
                dst[(size_t)(tq0 + mi * 16 + lc * 4 + v) * 256 + w * 32 + nio * 16 + lr] =
                    acco[mi][nio][v];
}

// ---------------------------------------------------------------------------
// k_reduce: out += sum over valid segments of part
// ---------------------------------------------------------------------------
__global__ __launch_bounds__(256) void k_reduce(const float* __restrict__ part,
                                                float* __restrict__ out,
                                                int SEGT, int nseg) {
    const int idx = blockIdx.x * 256 + threadIdx.x;   // f32x4 units, 262144
    const int jb  = idx >> 6;
    const int q   = jb >> 6;
    int ns = (q + SEGT) / SEGT;    // ceil((q+1)/SEGT)
    if (ns > nseg) ns = nseg;
    f32x4 acc = ((const f32x4*)out)[idx];
    for (int s = 0; s < ns; ++s)
        acc += *((const f32x4*)part + (size_t)s * 262144 + idx);
    ((f32x4*)out)[idx] = acc;
}

// ---------------------------------------------------------------------------
extern "C" void kernel_launch(void* const* d_in, const int* in_sizes, int n_in,
                              void* d_out, int out_size, void* d_ws, size_t ws_size,
                              hipStream_t stream) {
    const float* x  = (const float*)d_in[0];   // (512, 8, 256)
    const float* sw = (const float*)d_in[1];   // (1026, 256)
    const float* sb = (const float*)d_in[2];   // (1026,)
    const float* w0 = (const float*)d_in[3];   // (256, 256)
    float* out = (float*)d_out;                // (512, 8, 256)

    char* ws = (char*)d_ws;
    bf16*  WB  = (bf16*)(ws + 0);              // 344064 elems = 688,128 B
    bf16*  Xb  = (bf16*)(ws + 688128);         // 2 MB
    bf16*  A1B = (bf16*)(ws + 2785280);        // 2 MB
    bf16*  S1B = (bf16*)(ws + 4882432);        // 2 MB
    bf16*  A2g = (bf16*)(ws + 6979584);        // 2 MB
    bf16*  S2g = (bf16*)(ws + 9076736);        // 2 MB
    float* sag = (float*)(ws + 11173888);      // 16 KB
    float* ssg = (float*)(ws + 11190272);      // 16 KB
    float* part = (float*)(ws + 11206656);

    size_t partAvail = (ws_size > 11206656u) ? (ws_size - 11206656u) : 0;
    int nseg = (int)(partAvail / 4194304u);    // 4 MB per segment partial
    if (nseg > 22) nseg = 22;
    if (nseg < 1) nseg = 1;
    int SEGT = (64 + nseg - 1) / nseg;
    nseg = (64 + SEGT - 1) / SEGT;

    k_xb<<<1024, 256, 0, stream>>>(x, Xb);
    k_tw<<<84, 256, 0, stream>>>(sw, w0, WB);
    dim3 gp(64, 21);
    k_prep<<<gp, 256, 0, stream>>>(Xb, WB, sb, A1B, A2g, S1B, S2g, out, sag, ssg);
    dim3 ga(64, nseg);
    k_attn<<<ga, 512, 0, stream>>>(A2g, S2g, A1B, S1B, Xb, sag, ssg, part, SEGT);
    k_reduce<<<1024, 256, 0, stream>>>(part, out, SEGT, nseg);
}

// Round 7
// 124.733 us; speedup vs baseline: 2.2529x; 1.6225x over previous
//
#include <hip/hip_runtime.h>
#include <math.h>

typedef __bf16 bf16;
typedef __attribute__((ext_vector_type(4))) __bf16 bf16x4;
typedef __attribute__((ext_vector_type(8))) __bf16 bf16x8;
typedef __attribute__((ext_vector_type(4))) float f32x4;

#define MFMA16(a, b, c) __builtin_amdgcn_mfma_f32_16x16x32_bf16(a, b, c, 0, 0, 0)
#define NTQ 4096
#define NCH 32      // chunks (16 j-steps each)
#define CR  128     // rows per chunk (16 steps * 8 batch)

// ---------------------------------------------------------------------------
// k_xb: x f32 -> Xb bf16 (row-major 4096x256)
// ---------------------------------------------------------------------------
__global__ __launch_bounds__(256) void k_xb(const float* __restrict__ x,
                                            bf16* __restrict__ Xb) {
    const int idx = blockIdx.x * 256 + threadIdx.x;
    const float4 v = ((const float4*)x)[idx];
    bf16x4 o;
    o[0] = (bf16)v.x; o[1] = (bf16)v.y; o[2] = (bf16)v.z; o[3] = (bf16)v.w;
    ((bf16x4*)Xb)[idx] = o;
}

// ---------------------------------------------------------------------------
// k_tw: weights -> WB pre-swizzled MFMA B-fragment layout (bf16). (r6, verified)
// ---------------------------------------------------------------------------
__global__ __launch_bounds__(256) void k_tw(const float* __restrict__ sw,
                                            const float* __restrict__ w0,
                                            bf16* __restrict__ WB) {
    const int nb = blockIdx.x;                 // 0..83
    const int t = threadIdx.x, l = t & 63, kg = t >> 6;
    const int n = nb * 16 + (l & 15);
#pragma unroll
    for (int pass = 0; pass < 2; ++pass) {
        const int kk = kg + pass * 4;
        const int i0 = kk * 32 + (l >> 4) * 8;
        bf16x8 o;
        if (n < 1282) {
            const float* src = (n < 1024) ? (sw + (size_t)n * 256)
                             : (n < 1280) ? (w0 + (size_t)(n - 1024) * 256)
                                          : (sw + (size_t)(1024 + (n - 1280)) * 256);
#pragma unroll
            for (int e = 0; e < 8; ++e) o[e] = (bf16)src[i0 + e];
        } else {
#pragma unroll
            for (int e = 0; e < 8; ++e) o[e] = (bf16)0.0f;
        }
        *(bf16x8*)(WB + ((size_t)(nb * 8 + kk) * 64 + l) * 8) = o;
    }
}

// ---------------------------------------------------------------------------
// k_prep: MFMA GEMM C[4096 x 1282] = Xb @ W^T (+bias / sigmoid / layouts).
// grid (64 mb, 21 nb). nb 0..3 -> A1T[o][jb]; 4..7 -> A2g[jb][i] + A2T[i][jb];
// 8..11 -> S1T; 12..15 -> S2g + S2T; 16..19 -> out base f32; 20 -> gates.
// ---------------------------------------------------------------------------
__global__ __launch_bounds__(256) void k_prep(const bf16* __restrict__ Xb,
                                              const bf16* __restrict__ WB,
                                              const float* __restrict__ sb,
                                              bf16* __restrict__ A1T,
                                              bf16* __restrict__ S1T,
                                              bf16* __restrict__ A2g,
                                              bf16* __restrict__ S2g,
                                              bf16* __restrict__ A2T,
                                              bf16* __restrict__ S2T,
                                              float* __restrict__ out,
                                              float* __restrict__ sag,
                                              float* __restrict__ ssg) {
    const int mb = blockIdx.x, nb = blockIdx.y;
    const int t = threadIdx.x, l = t & 63, w = t >> 6;
    const int lr = l & 15, lc = l >> 4;
    const int rw = mb * 64 + w * 16;
    const int n0 = nb * 64;

    f32x4 acc[4];
#pragma unroll
    for (int ni = 0; ni < 4; ++ni) acc[ni] = (f32x4){0.f, 0.f, 0.f, 0.f};

#pragma unroll
    for (int kk = 0; kk < 8; ++kk) {
        const bf16x8 a = *(const bf16x8*)(Xb + (size_t)(rw + lr) * 256 + kk * 32 + lc * 8);
#pragma unroll
        for (int ni = 0; ni < 4; ++ni) {
            const bf16x8 b = *(const bf16x8*)(WB +
                ((size_t)((nb * 4 + ni) * 8 + kk) * 64 + l) * 8);
            acc[ni] = MFMA16(a, b, acc[ni]);
        }
    }

    if (nb == 20) {   // gates
        if (lr < 2) {
            const float bz = sb[1024 + lr];
            float* dst = lr ? ssg : sag;
#pragma unroll
            for (int v = 0; v < 4; ++v) {
                const float z = acc[0][v] + bz;
                dst[rw + lc * 4 + v] = 1.0f / (1.0f + expf(-z));
            }
        }
        return;
    }

    const int typ = nb >> 2;
    if (typ == 4) {   // base out (f32, no bias)
#pragma unroll
        for (int ni = 0; ni < 4; ++ni) {
            const int o = (n0 - 1024) + ni * 16 + lr;
#pragma unroll
            for (int v = 0; v < 4; ++v)
                out[(size_t)(rw + lc * 4 + v) * 256 + o] = acc[ni][v];
        }
        return;
    }

    if (typ == 0 || typ == 2) {   // A1 / S1 -> transposed [o][jb]
        bf16* dst = (typ == 0 ? A1T : S1T);
        const int ob = n0 - (typ == 0 ? 0 : 512);
#pragma unroll
        for (int ni = 0; ni < 4; ++ni) {
            const int o = ob + ni * 16 + lr;
            const float bz = sb[n0 + ni * 16 + lr];
            bf16x4 p;
#pragma unroll
            for (int v = 0; v < 4; ++v) p[v] = (bf16)(acc[ni][v] + bz);
            *(bf16x4*)(dst + (size_t)o * NTQ + rw + lc * 4) = p;
        }
    } else {                      // A2 / S2 -> row-major [jb][i] AND [i][jb]
        bf16* dstg = (typ == 1 ? A2g : S2g);
        bf16* dstt = (typ == 1 ? A2T : S2T);
        const int ib = n0 - (typ == 1 ? 256 : 768);
#pragma unroll
        for (int ni = 0; ni < 4; ++ni) {
            const int i = ib + ni * 16 + lr;
            const float bz = sb[n0 + ni * 16 + lr];
            bf16x4 p;
#pragma unroll
            for (int v = 0; v < 4; ++v) {
                const float fv = acc[ni][v] + bz;
                p[v] = (bf16)fv;
                dstg[(size_t)(rw + lc * 4 + v) * 256 + i] = (bf16)fv;
            }
            *(bf16x4*)(dstt + (size_t)i * NTQ + rw + lc * 4) = p;
        }
    }
}

// ---------------------------------------------------------------------------
// k_gate: materialize gate-scaled A-operand for delta GEMMs.
// At[c][b][o][k] bf16 (k in [0,256): k<128 -> +ga*A1T, k>=128 -> -gs*S1T)
// ---------------------------------------------------------------------------
__global__ __launch_bounds__(256) void k_gate(const bf16* __restrict__ A1T,
                                              const bf16* __restrict__ S1T,
                                              const float* __restrict__ sag,
                                              const float* __restrict__ ssg,
                                              bf16* __restrict__ At) {
    const int idx = blockIdx.x * 256 + threadIdx.x;   // 2,097,152 vec8 units
    const int klv = idx & 31;
    const int o   = (idx >> 5) & 255;
    const int b   = (idx >> 13) & 7;
    const int c   = idx >> 16;
    const int k0  = klv * 8;

    const bf16* src;
    float g;
    int r0;
    if (k0 < 128) {
        r0 = c * CR + k0;
        src = A1T + (size_t)o * NTQ + r0;
        g = sag[(r0 >> 3) * 8 + b];
    } else {
        r0 = c * CR + (k0 - 128);
        src = S1T + (size_t)o * NTQ + r0;
        g = -ssg[(r0 >> 3) * 8 + b];
    }
    const bf16x8 s = *(const bf16x8*)src;
    bf16x8 ov;
#pragma unroll
    for (int e = 0; e < 8; ++e) ov[e] = (bf16)(g * (float)s[e]);
    *(bf16x8*)(At + ((size_t)((c * 8 + b) * 256 + o) * 256) + k0) = ov;
}

// ---------------------------------------------------------------------------
// k_delta: per (c,b): delta[256 o][256 i] = At_cb^T-form GEMM, K=256.
// 512 blocks (c, b, oh), 8 waves (2 ow x 4 iw), 128 MFMA/wave. No barriers.
// Output: SPD bf16 [c][b][o][i] (later overwritten in-place by prefix states).
// ---------------------------------------------------------------------------
__global__ __launch_bounds__(512) void k_delta(const bf16* __restrict__ At,
                                               const bf16* __restrict__ A2T,
                                               const bf16* __restrict__ S2T,
                                               bf16* __restrict__ SPD) {
    const int bid = blockIdx.x;
    const int oh = bid & 1, bb = (bid >> 1) & 7, c = bid >> 4;
    const int t = threadIdx.x, l = t & 63, w = t >> 6;
    const int lr = l & 15, lc = l >> 4;
    const int o0 = oh * 128 + (w >> 2) * 64;
    const int i0 = (w & 3) * 64;

    const bf16* Ab = At + (size_t)((c * 8 + bb) * 256) * 256;

    f32x4 acc[4][4];
#pragma unroll
    for (int mi = 0; mi < 4; ++mi)
#pragma unroll
        for (int ni = 0; ni < 4; ++ni) acc[mi][ni] = (f32x4){0.f, 0.f, 0.f, 0.f};

#pragma unroll
    for (int kk = 0; kk < 8; ++kk) {
        bf16x8 a[4];
#pragma unroll
        for (int mi = 0; mi < 4; ++mi)
            a[mi] = *(const bf16x8*)(Ab + (size_t)(o0 + mi * 16 + lr) * 256 +
                                     kk * 32 + lc * 8);
        const bf16* Bsrc = (kk < 4) ? A2T : S2T;
        const int kb = c * CR + (kk & 3) * 32 + lc * 8;
#pragma unroll
        for (int ni = 0; ni < 4; ++ni) {
            const bf16x8 b = *(const bf16x8*)(Bsrc +
                (size_t)(i0 + ni * 16 + lr) * NTQ + kb);
#pragma unroll
            for (int mi = 0; mi < 4; ++mi)
                acc[mi][ni] = MFMA16(a[mi], b, acc[mi][ni]);
        }
    }

    bf16* dst = SPD + (size_t)((c * 8 + bb) * 256) * 256;
#pragma unroll
    for (int mi = 0; mi < 4; ++mi)
#pragma unroll
        for (int ni = 0; ni < 4; ++ni)
#pragma unroll
            for (int v = 0; v < 4; ++v)
                dst[(size_t)(o0 + mi * 16 + lc * 4 + v) * 256 + i0 + ni * 16 + lr] =
                    (bf16)(acc[mi][ni][v]);
}

// ---------------------------------------------------------------------------
// k_prefix: in-place exclusive prefix over chunks: SPD[c] <- sum_{c'<c} delta[c']
// Thread owns (b,o,ivec8); loops c sequentially (32 iters).
// ---------------------------------------------------------------------------
__global__ __launch_bounds__(256) void k_prefix(bf16* __restrict__ SPD) {
    const int idx = blockIdx.x * 256 + threadIdx.x;   // 65536 units
    const int ivv = idx & 31;
    const int o   = (idx >> 5) & 255;
    const int bb  = idx >> 13;
    float run[8];
#pragma unroll
    for (int e = 0; e < 8; ++e) run[e] = 0.f;
    for (int c = 0; c < NCH; ++c) {
        bf16* p = SPD + ((size_t)((c * 8 + bb) * 256 + o) * 256) + ivv * 8;
        const bf16x8 d = *(const bf16x8*)p;
        bf16x8 s;
#pragma unroll
        for (int e = 0; e < 8; ++e) s[e] = (bf16)run[e];
        *(bf16x8*)p = s;
#pragma unroll
        for (int e = 0; e < 8; ++e) run[e] += (float)d[e];
    }
}

// ---------------------------------------------------------------------------
// k_apply: out[jb][o] += sum_i Xb[jb][i] * SPD[c][b][o][i]  (inter-chunk part)
// 256 blocks (c,b), 4 waves; M=16 chunk-rows of batch b, N=256, K=256.
// ---------------------------------------------------------------------------
__global__ __launch_bounds__(256) void k_apply(const bf16* __restrict__ Xb,
                                               const bf16* __restrict__ SPD,
                                               float* __restrict__ out) {
    const int bid = blockIdx.x;
    const int bb = bid & 7, c = bid >> 3;
    const int t = threadIdx.x, l = t & 63, w = t >> 6;
    const int lr = l & 15, lc = l >> 4;

    f32x4 acc[4];
#pragma unroll
    for (int ni = 0; ni < 4; ++ni) acc[ni] = (f32x4){0.f, 0.f, 0.f, 0.f};

    const bf16* Sp = SPD + (size_t)((c * 8 + bb) * 256) * 256;
#pragma unroll
    for (int kk = 0; kk < 8; ++kk) {
        const bf16x8 a = *(const bf16x8*)(Xb +
            (size_t)((c * 16 + lr) * 8 + bb) * 256 + kk * 32 + lc * 8);
#pragma unroll
        for (int ni = 0; ni < 4; ++ni) {
            const bf16x8 b = *(const bf16x8*)(Sp +
                (size_t)(w * 64 + ni * 16 + lr) * 256 + kk * 32 + lc * 8);
            acc[ni] = MFMA16(a, b, acc[ni]);
        }
    }

#pragma unroll
    for (int ni = 0; ni < 4; ++ni) {
        const int o = w * 64 + ni * 16 + lr;
#pragma unroll
        for (int v = 0; v < 4; ++v) {
            const size_t jb = (size_t)(c * 16 + lc * 4 + v) * 8 + bb;
            out[jb * 256 + o] += acc[ni][v];
        }
    }
}

// ---------------------------------------------------------------------------
// k_intra: intra-chunk causal part. 64 blocks (c, qi); q-tile = 64 rows
// (tq0 = (c*2+qi)*64), keys = kt-tiles kg = c*2 .. c*2+qi (1 or 2 iters).
// Structure = r6 verified iter (8 waves, ih/sub, PT merge, PB, out MFMA),
// T-operands read from A1T/S1T row-major; epilogue RMW adds into out.
// ---------------------------------------------------------------------------
__global__ __launch_bounds__(512, 2) void k_intra(const bf16* __restrict__ A2g,
                                                  const bf16* __restrict__ S2g,
                                                  const bf16* __restrict__ A1T,
                                                  const bf16* __restrict__ S1T,
                                                  const bf16* __restrict__ Xb,
                                                  const float* __restrict__ sag,
                                                  const float* __restrict__ ssg,
                                                  float* __restrict__ out) {
    const int bid = blockIdx.x;
    const int qi = bid & 1, c = bid >> 1;
    const int qg = c * 2 + qi;          // global 64-row q-tile
    const int tq0 = qg * 64;

    const int tid = threadIdx.x, l = tid & 63, w = tid >> 6;
    const int lr = l & 15, lc = l >> 4;
    const int ih = w >> 2, sub = w & 3;

    __shared__ __align__(16) float PTa[128 * 34];
    __shared__ __align__(16) float PTb[128 * 34];
    __shared__ __align__(16) bf16 PB[64][136];
    __shared__ float ga[64], gs[64];

    bf16x8 xa[4][4];
#pragma unroll
    for (int mi = 0; mi < 4; ++mi)
#pragma unroll
        for (int kk = 0; kk < 4; ++kk)
            xa[mi][kk] = *(const bf16x8*)(Xb + (size_t)(tq0 + mi * 16 + lr) * 256 +
                                          ih * 128 + kk * 32 + lc * 8);

    f32x4 acco[4][2];
#pragma unroll
    for (int mi = 0; mi < 4; ++mi)
#pragma unroll
        for (int ni = 0; ni < 2; ++ni) acco[mi][ni] = (f32x4){0.f, 0.f, 0.f, 0.f};

    const bf16* Bsrc = (sub < 2) ? A2g : S2g;
    const float sgn  = (sub < 2) ? 1.f : -1.f;

    for (int kg = c * 2; kg <= c * 2 + qi; ++kg) {
        const int TK0 = kg * 64;
        if (tid < 64) ga[tid] = sag[TK0 + tid];
        else if (tid < 128) gs[tid - 64] = ssg[TK0 + tid - 64];

        f32x4 accs[4][2];
#pragma unroll
        for (int mi = 0; mi < 4; ++mi)
#pragma unroll
            for (int ni = 0; ni < 2; ++ni) accs[mi][ni] = (f32x4){0.f, 0.f, 0.f, 0.f};
#pragma unroll
        for (int kk = 0; kk < 4; ++kk) {
#pragma unroll
            for (int ni = 0; ni < 2; ++ni) {
                const bf16x8 bfg = *(const bf16x8*)(Bsrc +
                    (size_t)(TK0 + (sub & 1) * 32 + ni * 16 + lr) * 256 +
                    ih * 128 + kk * 32 + lc * 8);
#pragma unroll
                for (int mi = 0; mi < 4; ++mi)
                    accs[mi][ni] = MFMA16(xa[mi][kk], bfg, accs[mi][ni]);
            }
        }

        float* PTw = ih ? PTb : PTa;
        const int mw = 2 - 2 * ih;
#pragma unroll
        for (int mk = 0; mk < 2; ++mk)
#pragma unroll
            for (int ni = 0; ni < 2; ++ni) {
                const int cL = sub * 32 + ni * 16 + lr;
                *(f32x4*)&PTw[cL * 34 + mk * 16 + lc * 4] = accs[mw + mk][ni];
            }
        __syncthreads();

        const float* PTr = ih ? PTa : PTb;
        const int mo = 2 * ih;
#pragma unroll
        for (int mk = 0; mk < 2; ++mk)
#pragma unroll
            for (int ni = 0; ni < 2; ++ni) {
                const int cL  = sub * 32 + ni * 16 + lr;
                const int tkL = cL & 63;
                const f32x4 oth = *(const f32x4*)&PTr[cL * 34 + mk * 16 + lc * 4];
#pragma unroll
                for (int v = 0; v < 4; ++v) {
                    const int row = ih * 32 + mk * 16 + lc * 4 + v;
                    const float gg = (sub < 2 ? ga : gs)[(tkL & 56) + (row & 7)];
                    float p = sgn * gg * (accs[mo + mk][ni][v] + oth[v]);
                    const int ks = kg * 8 + (tkL >> 3);
                    const int js = qg * 8 + (row >> 3);
                    if (ks > js) p = 0.f;
                    PB[row][cL] = (bf16)p;
                }
            }
        __syncthreads();

#pragma unroll
        for (int kk2 = 0; kk2 < 4; ++kk2) {
            const bf16* Tsrc = (kk2 < 2) ? A1T : S1T;
            bf16x8 af[4];
#pragma unroll
            for (int mi = 0; mi < 4; ++mi)
                af[mi] = *(const bf16x8*)&PB[mi * 16 + lr][kk2 * 32 + lc * 8];
#pragma unroll
            for (int nio = 0; nio < 2; ++nio) {
                const bf16x8 bfg = *(const bf16x8*)(Tsrc +
                    (size_t)(w * 32 + nio * 16 + lr) * NTQ +
                    TK0 + (kk2 & 1) * 32 + lc * 8);
#pragma unroll
                for (int mi = 0; mi < 4; ++mi)
                    acco[mi][nio] = MFMA16(af[mi], bfg, acco[mi][nio]);
            }
        }
        __syncthreads();   // PB/PT reuse safety for 2nd iter
    }

#pragma unroll
    for (int mi = 0; mi < 4; ++mi)
#pragma unroll
        for (int nio = 0; nio < 2; ++nio)
#pragma unroll
            for (int v = 0; v < 4; ++v)
                out[(size_t)(tq0 + mi * 16 + lc * 4 + v) * 256 +
                    w * 32 + nio * 16 + lr] += acco[mi][nio][v];
}

// ---------------------------------------------------------------------------
extern "C" void kernel_launch(void* const* d_in, const int* in_sizes, int n_in,
                              void* d_out, int out_size, void* d_ws, size_t ws_size,
                              hipStream_t stream) {
    const float* x  = (const float*)d_in[0];   // (512, 8, 256)
    const float* sw = (const float*)d_in[1];   // (1026, 256)
    const float* sb = (const float*)d_in[2];   // (1026,)
    const float* w0 = (const float*)d_in[3];   // (256, 256)
    float* out = (float*)d_out;                // (512, 8, 256)

    char* ws = (char*)d_ws;
    bf16*  WB  = (bf16*)(ws + 0);              // 688,128 B
    bf16*  Xb  = (bf16*)(ws + 688128);         // 2 MB
    bf16*  A1T = (bf16*)(ws + 2785280);        // 2 MB
    bf16*  S1T = (bf16*)(ws + 4882432);        // 2 MB
    bf16*  A2g = (bf16*)(ws + 6979584);        // 2 MB
    bf16*  S2g = (bf16*)(ws + 9076736);        // 2 MB
    bf16*  A2T = (bf16*)(ws + 11173888);       // 2 MB
    bf16*  S2T = (bf16*)(ws + 13271040);       // 2 MB
    float* sag = (float*)(ws + 15368192);      // 16 KB
    float* ssg = (float*)(ws + 15384576);      // 16 KB
    bf16*  At  = (bf16*)(ws + 15400960);       // 32 MB
    bf16*  SPD = (bf16*)(ws + 48955392);       // 32 MB (delta -> prefix states)

    k_xb<<<1024, 256, 0, stream>>>(x, Xb);
    k_tw<<<84, 256, 0, stream>>>(sw, w0, WB);
    dim3 gp(64, 21);
    k_prep<<<gp, 256, 0, stream>>>(Xb, WB, sb, A1T, S1T, A2g, S2g, A2T, S2T,
                                   out, sag, ssg);
    k_gate<<<8192, 256, 0, stream>>>(A1T, S1T, sag, ssg, At);
    k_delta<<<512, 512, 0, stream>>>(At, A2T, S2T, SPD);
    k_prefix<<<256, 256, 0, stream>>>(SPD);
    k_apply<<<256, 256, 0, stream>>>(Xb, SPD, out);
    k_intra<<<64, 512, 0, stream>>>(A2g, S2g, A1T, S1T, Xb, sag, ssg, out);
}

// Round 8
// 99.864 us; speedup vs baseline: 2.8140x; 1.2490x over previous
//
#include <hip/hip_runtime.h>
#include <math.h>

typedef __bf16 bf16;
typedef __attribute__((ext_vector_type(4))) __bf16 bf16x4;
typedef __attribute__((ext_vector_type(8))) __bf16 bf16x8;
typedef __attribute__((ext_vector_type(4))) float f32x4;

#define MFMA16(a, b, c) __builtin_amdgcn_mfma_f32_16x16x32_bf16(a, b, c, 0, 0, 0)
#define NTQ 4096
#define NCH 32      // chunks (16 j-steps each)

// ---------------------------------------------------------------------------
// k_init: fused  [bid<1024] x f32 -> Xb bf16   |   [bid>=1024] weights -> WB
// WB pre-swizzled MFMA B-fragment layout (r6/r7 verified).
// ---------------------------------------------------------------------------
__global__ __launch_bounds__(256) void k_init(const float* __restrict__ x,
                                              const float* __restrict__ sw,
                                              const float* __restrict__ w0,
                                              bf16* __restrict__ Xb,
                                              bf16* __restrict__ WB) {
    const int bid = blockIdx.x;
    if (bid < 1024) {
        const int idx = bid * 256 + threadIdx.x;
        const float4 v = ((const float4*)x)[idx];
        bf16x4 o;
        o[0] = (bf16)v.x; o[1] = (bf16)v.y; o[2] = (bf16)v.z; o[3] = (bf16)v.w;
        ((bf16x4*)Xb)[idx] = o;
        return;
    }
    const int nb = bid - 1024;                 // 0..83
    const int t = threadIdx.x, l = t & 63, kg = t >> 6;
    const int n = nb * 16 + (l & 15);
#pragma unroll
    for (int pass = 0; pass < 2; ++pass) {
        const int kk = kg + pass * 4;
        const int i0 = kk * 32 + (l >> 4) * 8;
        bf16x8 o;
        if (n < 1282) {
            const float* src = (n < 1024) ? (sw + (size_t)n * 256)
                             : (n < 1280) ? (w0 + (size_t)(n - 1024) * 256)
                                          : (sw + (size_t)(1024 + (n - 1280)) * 256);
#pragma unroll
            for (int e = 0; e < 8; ++e) o[e] = (bf16)src[i0 + e];
        } else {
#pragma unroll
            for (int e = 0; e < 8; ++e) o[e] = (bf16)0.0f;
        }
        *(bf16x8*)(WB + ((size_t)(nb * 8 + kk) * 64 + l) * 8) = o;
    }
}

// ---------------------------------------------------------------------------
// k_prep: MFMA GEMM C[4096 x 1282] = Xb @ W^T (+bias / sigmoid / layouts).
// (r7, verified) nb 0..3 -> A1T[o][jb]; 4..7 -> A2g[jb][i] + A2T[i][jb];
// 8..11 -> S1T; 12..15 -> S2g + S2T; 16..19 -> out base f32; 20 -> gates.
// ---------------------------------------------------------------------------
__global__ __launch_bounds__(256) void k_prep(const bf16* __restrict__ Xb,
                                              const bf16* __restrict__ WB,
                                              const float* __restrict__ sb,
                                              bf16* __restrict__ A1T,
                                              bf16* __restrict__ S1T,
                                              bf16* __restrict__ A2g,
                                              bf16* __restrict__ S2g,
                                              bf16* __restrict__ A2T,
                                              bf16* __restrict__ S2T,
                                              float* __restrict__ out,
                                              float* __restrict__ sag,
                                              float* __restrict__ ssg) {
    const int mb = blockIdx.x, nb = blockIdx.y;
    const int t = threadIdx.x, l = t & 63, w = t >> 6;
    const int lr = l & 15, lc = l >> 4;
    const int rw = mb * 64 + w * 16;
    const int n0 = nb * 64;

    f32x4 acc[4];
#pragma unroll
    for (int ni = 0; ni < 4; ++ni) acc[ni] = (f32x4){0.f, 0.f, 0.f, 0.f};

#pragma unroll
    for (int kk = 0; kk < 8; ++kk) {
        const bf16x8 a = *(const bf16x8*)(Xb + (size_t)(rw + lr) * 256 + kk * 32 + lc * 8);
#pragma unroll
        for (int ni = 0; ni < 4; ++ni) {
            const bf16x8 b = *(const bf16x8*)(WB +
                ((size_t)((nb * 4 + ni) * 8 + kk) * 64 + l) * 8);
            acc[ni] = MFMA16(a, b, acc[ni]);
        }
    }

    if (nb == 20) {   // gates
        if (lr < 2) {
            const float bz = sb[1024 + lr];
            float* dst = lr ? ssg : sag;
#pragma unroll
            for (int v = 0; v < 4; ++v) {
                const float z = acc[0][v] + bz;
                dst[rw + lc * 4 + v] = 1.0f / (1.0f + expf(-z));
            }
        }
        return;
    }

    const int typ = nb >> 2;
    if (typ == 4) {   // base out (f32, no bias)
#pragma unroll
        for (int ni = 0; ni < 4; ++ni) {
            const int o = (n0 - 1024) + ni * 16 + lr;
#pragma unroll
            for (int v = 0; v < 4; ++v)
                out[(size_t)(rw + lc * 4 + v) * 256 + o] = acc[ni][v];
        }
        return;
    }

    if (typ == 0 || typ == 2) {   // A1 / S1 -> transposed [o][jb]
        bf16* dst = (typ == 0 ? A1T : S1T);
        const int ob = n0 - (typ == 0 ? 0 : 512);
#pragma unroll
        for (int ni = 0; ni < 4; ++ni) {
            const int o = ob + ni * 16 + lr;
            const float bz = sb[n0 + ni * 16 + lr];
            bf16x4 p;
#pragma unroll
            for (int v = 0; v < 4; ++v) p[v] = (bf16)(acc[ni][v] + bz);
            *(bf16x4*)(dst + (size_t)o * NTQ + rw + lc * 4) = p;
        }
    } else {                      // A2 / S2 -> row-major [jb][i] AND [i][jb]
        bf16* dstg = (typ == 1 ? A2g : S2g);
        bf16* dstt = (typ == 1 ? A2T : S2T);
        const int ib = n0 - (typ == 1 ? 256 : 768);
#pragma unroll
        for (int ni = 0; ni < 4; ++ni) {
            const int i = ib + ni * 16 + lr;
            const float bz = sb[n0 + ni * 16 + lr];
            bf16x4 p;
#pragma unroll
            for (int v = 0; v < 4; ++v) {
                const float fv = acc[ni][v] + bz;
                p[v] = (bf16)fv;
                dstg[(size_t)(rw + lc * 4 + v) * 256 + i] = (bf16)fv;
            }
            *(bf16x4*)(dstt + (size_t)i * NTQ + rw + lc * 4) = p;
        }
    }
}

// ---------------------------------------------------------------------------
// k_delta: per (c,b): delta[256 o][256 i], K=128 (a) + 128 (s), gate fused.
// 512 blocks (c, b, oh), 8 waves, no barriers. A-frags read from A1T/S1T
// and scaled in-register by +sag/-ssg (per-fragment scalar). -> SPD bf16.
// ---------------------------------------------------------------------------
__global__ __launch_bounds__(512) void k_delta(const bf16* __restrict__ A1T,
                                               const bf16* __restrict__ S1T,
                                               const bf16* __restrict__ A2T,
                                               const bf16* __restrict__ S2T,
                                               const float* __restrict__ sag,
                                               const float* __restrict__ ssg,
                                               bf16* __restrict__ SPD) {
    const int bid = blockIdx.x;
    const int oh = bid & 1, bb = (bid >> 1) & 7, c = bid >> 4;
    const int t = threadIdx.x, l = t & 63, w = t >> 6;
    const int lr = l & 15, lc = l >> 4;
    const int o0 = oh * 128 + (w >> 2) * 64;
    const int i0 = (w & 3) * 64;

    // gates for this lane's k-slots: t_local = ta*4 + lc
    float gA[4], gS[4];
#pragma unroll
    for (int ta = 0; ta < 4; ++ta) {
        gA[ta] = sag[(c * 16 + ta * 4 + lc) * 8 + bb];
        gS[ta] = -ssg[(c * 16 + ta * 4 + lc) * 8 + bb];
    }

    f32x4 acc[4][4];
#pragma unroll
    for (int mi = 0; mi < 4; ++mi)
#pragma unroll
        for (int ni = 0; ni < 4; ++ni) acc[mi][ni] = (f32x4){0.f, 0.f, 0.f, 0.f};

#pragma unroll
    for (int kk = 0; kk < 8; ++kk) {
        const bf16* Asrc = (kk < 4) ? A1T : S1T;
        const bf16* Bsrc = (kk < 4) ? A2T : S2T;
        const float g = (kk < 4) ? gA[kk & 3] : gS[kk & 3];
        const int jb0 = c * 128 + (kk & 3) * 32 + lc * 8;
        bf16x8 a[4];
#pragma unroll
        for (int mi = 0; mi < 4; ++mi) {
            const bf16x8 raw = *(const bf16x8*)(Asrc +
                (size_t)(o0 + mi * 16 + lr) * NTQ + jb0);
#pragma unroll
            for (int e = 0; e < 8; ++e) a[mi][e] = (bf16)(g * (float)raw[e]);
        }
#pragma unroll
        for (int ni = 0; ni < 4; ++ni) {
            const bf16x8 b = *(const bf16x8*)(Bsrc +
                (size_t)(i0 + ni * 16 + lr) * NTQ + jb0);
#pragma unroll
            for (int mi = 0; mi < 4; ++mi)
                acc[mi][ni] = MFMA16(a[mi], b, acc[mi][ni]);
        }
    }

    bf16* dst = SPD + (size_t)((c * 8 + bb) * 256) * 256;
#pragma unroll
    for (int mi = 0; mi < 4; ++mi)
#pragma unroll
        for (int ni = 0; ni < 4; ++ni)
#pragma unroll
            for (int v = 0; v < 4; ++v)
                dst[(size_t)(o0 + mi * 16 + lc * 4 + v) * 256 + i0 + ni * 16 + lr] =
                    (bf16)(acc[mi][ni][v]);
}

// ---------------------------------------------------------------------------
// k_prefix: in-place exclusive prefix over chunks (32 sequential iters/thread).
// ---------------------------------------------------------------------------
__global__ __launch_bounds__(256) void k_prefix(bf16* __restrict__ SPD) {
    const int idx = blockIdx.x * 256 + threadIdx.x;   // 65536 units
    const int ivv = idx & 31;
    const int o   = (idx >> 5) & 255;
    const int bb  = idx >> 13;
    float run[8];
#pragma unroll
    for (int e = 0; e < 8; ++e) run[e] = 0.f;
    for (int c = 0; c < NCH; ++c) {
        bf16* p = SPD + ((size_t)((c * 8 + bb) * 256 + o) * 256) + ivv * 8;
        const bf16x8 d = *(const bf16x8*)p;
        bf16x8 s;
#pragma unroll
        for (int e = 0; e < 8; ++e) s[e] = (bf16)run[e];
        *(bf16x8*)p = s;
#pragma unroll
        for (int e = 0; e < 8; ++e) run[e] += (float)d[e];
    }
}

// ---------------------------------------------------------------------------
// k_out: fused inter (X @ SPD^T) + intra-chunk causal part. Block (c,b),
// 4 waves; block exclusively owns out rows (c*16..+16)*8+b -> one RMW, no race.
// Intra: S(16x256) in regs -> gate/mask in C-layout -> PB LDS (1 barrier) ->
// out-phase. Inter shares X fragments with intra S-phase.
// ---------------------------------------------------------------------------
__global__ __launch_bounds__(256) void k_out(const bf16* __restrict__ Xb,
                                             const bf16* __restrict__ SPD,
                                             const bf16* __restrict__ A2g,
                                             const bf16* __restrict__ S2g,
                                             const bf16* __restrict__ A1T,
                                             const bf16* __restrict__ S1T,
                                             const float* __restrict__ sag,
                                             const float* __restrict__ ssg,
                                             float* __restrict__ out) {
    const int bid = blockIdx.x;
    const int bb = bid & 7, c = bid >> 3;
    const int t = threadIdx.x, l = t & 63, w = t >> 6;
    const int lr = l & 15, lc = l >> 4;
    const int o0 = w * 64;

    __shared__ __align__(16) bf16 PB[16][264];

    // X fragments: rows j=lr of (chunk c, batch bb), k = i
    bf16x8 xa[8];
#pragma unroll
    for (int kk = 0; kk < 8; ++kk)
        xa[kk] = *(const bf16x8*)(Xb +
            (size_t)((c * 16 + lr) * 8 + bb) * 256 + kk * 32 + lc * 8);

    // ---- intra S phase: wave w owns score n-tiles nt=2w,2w+1 (a & s parts) ----
    f32x4 accsA[2], accsS[2];
#pragma unroll
    for (int ni = 0; ni < 2; ++ni) {
        accsA[ni] = (f32x4){0.f, 0.f, 0.f, 0.f};
        accsS[ni] = (f32x4){0.f, 0.f, 0.f, 0.f};
    }
#pragma unroll
    for (int kk = 0; kk < 8; ++kk) {
#pragma unroll
        for (int ni = 0; ni < 2; ++ni) {
            const size_t roff = (size_t)(c * 128 + (2 * w + ni) * 16 + lr) * 256 +
                                kk * 32 + lc * 8;
            const bf16x8 ba = *(const bf16x8*)(A2g + roff);
            accsA[ni] = MFMA16(xa[kk], ba, accsA[ni]);
            const bf16x8 bs = *(const bf16x8*)(S2g + roff);
            accsS[ni] = MFMA16(xa[kk], bs, accsS[ni]);
        }
    }

    // gate + causal mask in C-layout (row j = lc*4+v, key col local = lr)
#pragma unroll
    for (int ni = 0; ni < 2; ++ni) {
        const int rl = (2 * w + ni) * 16 + lr;      // key row local 0..127
        const int tl = rl >> 3;                     // key step local 0..15
        const float ga =  sag[(c * 16 + tl) * 8 + bb];
        const float gs = -ssg[(c * 16 + tl) * 8 + bb];
#pragma unroll
        for (int v = 0; v < 4; ++v) {
            const int j = lc * 4 + v;
            const bool m = (tl > j);
            PB[j][rl]       = (bf16)(m ? 0.f : ga * accsA[ni][v]);
            PB[j][128 + rl] = (bf16)(m ? 0.f : gs * accsS[ni][v]);
        }
    }

    // ---- inter part while PB settles: acco += X @ SPD[c,b]^T ----
    f32x4 acco[4];
#pragma unroll
    for (int ni = 0; ni < 4; ++ni) acco[ni] = (f32x4){0.f, 0.f, 0.f, 0.f};
    const bf16* Sp = SPD + (size_t)((c * 8 + bb) * 256) * 256;
#pragma unroll
    for (int kk = 0; kk < 8; ++kk) {
#pragma unroll
        for (int ni = 0; ni < 4; ++ni) {
            const bf16x8 b = *(const bf16x8*)(Sp +
                (size_t)(o0 + ni * 16 + lr) * 256 + kk * 32 + lc * 8);
            acco[ni] = MFMA16(xa[kk], b, acco[ni]);
        }
    }

    __syncthreads();   // PB visible

    // ---- intra out phase: K' = 256 (a rows 0..127 from A1T, s from S1T) ----
#pragma unroll
    for (int kk2 = 0; kk2 < 8; ++kk2) {
        const bf16* Tsrc = (kk2 < 4) ? A1T : S1T;
        const bf16x8 af = *(const bf16x8*)&PB[lr][kk2 * 32 + lc * 8];
        const int jb0 = c * 128 + (kk2 & 3) * 32 + lc * 8;
#pragma unroll
        for (int ni = 0; ni < 4; ++ni) {
            const bf16x8 b = *(const bf16x8*)(Tsrc +
                (size_t)(o0 + ni * 16 + lr) * NTQ + jb0);
            acco[ni] = MFMA16(af, b, acco[ni]);
        }
    }

    // ---- single RMW into out ----
#pragma unroll
    for (int ni = 0; ni < 4; ++ni) {
        const int o = o0 + ni * 16 + lr;
#pragma unroll
        for (int v = 0; v < 4; ++v) {
            const size_t jb = (size_t)((c * 16 + lc * 4 + v) * 8 + bb);
            out[jb * 256 + o] += acco[ni][v];
        }
    }
}

// ---------------------------------------------------------------------------
extern "C" void kernel_launch(void* const* d_in, const int* in_sizes, int n_in,
                              void* d_out, int out_size, void* d_ws, size_t ws_size,
                              hipStream_t stream) {
    const float* x  = (const float*)d_in[0];   // (512, 8, 256)
    const float* sw = (const float*)d_in[1];   // (1026, 256)
    const float* sb = (const float*)d_in[2];   // (1026,)
    const float* w0 = (const float*)d_in[3];   // (256, 256)
    float* out = (float*)d_out;                // (512, 8, 256)

    char* ws = (char*)d_ws;
    bf16*  WB  = (bf16*)(ws + 0);              // 688,128 B
    bf16*  Xb  = (bf16*)(ws + 688128);         // 2 MB
    bf16*  A1T = (bf16*)(ws + 2785280);        // 2 MB
    bf16*  S1T = (bf16*)(ws + 4882432);        // 2 MB
    bf16*  A2g = (bf16*)(ws + 6979584);        // 2 MB
    bf16*  S2g = (bf16*)(ws + 9076736);        // 2 MB
    bf16*  A2T = (bf16*)(ws + 11173888);       // 2 MB
    bf16*  S2T = (bf16*)(ws + 13271040);       // 2 MB
    float* sag = (float*)(ws + 15368192);      // 16 KB
    float* ssg = (float*)(ws + 15384576);      // 16 KB
    bf16*  SPD = (bf16*)(ws + 15400960);       // 32 MB (delta -> prefix states)

    k_init<<<1108, 256, 0, stream>>>(x, sw, w0, Xb, WB);
    dim3 gp(64, 21);
    k_prep<<<gp, 256, 0, stream>>>(Xb, WB, sb, A1T, S1T, A2g, S2g, A2T, S2T,
                                   out, sag, ssg);
    k_delta<<<512, 512, 0, stream>>>(A1T, S1T, A2T, S2T, sag, ssg, SPD);
    k_prefix<<<256, 256, 0, stream>>>(SPD);
    k_out<<<256, 256, 0, stream>>>(Xb, SPD, A2g, S2g, A1T, S1T, sag, ssg, out);
}

// Round 9
// 99.619 us; speedup vs baseline: 2.8209x; 1.0025x over previous
//
#include <hip/hip_runtime.h>
#include <math.h>

typedef __bf16 bf16;
typedef __attribute__((ext_vector_type(4))) __bf16 bf16x4;
typedef __attribute__((ext_vector_type(8))) __bf16 bf16x8;
typedef __attribute__((ext_vector_type(4))) float f32x4;

#define MFMA16(a, b, c) __builtin_amdgcn_mfma_f32_16x16x32_bf16(a, b, c, 0, 0, 0)
#define NTQ 4096
#define NCH 32      // chunks (16 j-steps each)

// ---------------------------------------------------------------------------
// k_init: fused  [bid<1024] x f32 -> Xb bf16   |   [bid>=1024] weights -> WB
// ---------------------------------------------------------------------------
__global__ __launch_bounds__(256) void k_init(const float* __restrict__ x,
                                              const float* __restrict__ sw,
                                              const float* __restrict__ w0,
                                              bf16* __restrict__ Xb,
                                              bf16* __restrict__ WB) {
    const int bid = blockIdx.x;
    if (bid < 1024) {
        const int idx = bid * 256 + threadIdx.x;
        const float4 v = ((const float4*)x)[idx];
        bf16x4 o;
        o[0] = (bf16)v.x; o[1] = (bf16)v.y; o[2] = (bf16)v.z; o[3] = (bf16)v.w;
        ((bf16x4*)Xb)[idx] = o;
        return;
    }
    const int nb = bid - 1024;                 // 0..83
    const int t = threadIdx.x, l = t & 63, kg = t >> 6;
    const int n = nb * 16 + (l & 15);
#pragma unroll
    for (int pass = 0; pass < 2; ++pass) {
        const int kk = kg + pass * 4;
        const int i0 = kk * 32 + (l >> 4) * 8;
        bf16x8 o;
        if (n < 1282) {
            const float* src = (n < 1024) ? (sw + (size_t)n * 256)
                             : (n < 1280) ? (w0 + (size_t)(n - 1024) * 256)
                                          : (sw + (size_t)(1024 + (n - 1280)) * 256);
#pragma unroll
            for (int e = 0; e < 8; ++e) o[e] = (bf16)src[i0 + e];
        } else {
#pragma unroll
            for (int e = 0; e < 8; ++e) o[e] = (bf16)0.0f;
        }
        *(bf16x8*)(WB + ((size_t)(nb * 8 + kk) * 64 + l) * 8) = o;
    }
}

// ---------------------------------------------------------------------------
// k_prep: MFMA GEMM C[4096 x 1282] = Xb @ W^T (+bias / sigmoid / layouts).
// (r7/r8 verified) nb 0..3 -> A1T[o][jb]; 4..7 -> A2g + A2T; 8..11 -> S1T;
// 12..15 -> S2g + S2T; 16..19 -> out base f32; 20 -> gates.
// ---------------------------------------------------------------------------
__global__ __launch_bounds__(256) void k_prep(const bf16* __restrict__ Xb,
                                              const bf16* __restrict__ WB,
                                              const float* __restrict__ sb,
                                              bf16* __restrict__ A1T,
                                              bf16* __restrict__ S1T,
                                              bf16* __restrict__ A2g,
                                              bf16* __restrict__ S2g,
                                              bf16* __restrict__ A2T,
                                              bf16* __restrict__ S2T,
                                              float* __restrict__ out,
                                              float* __restrict__ sag,
                                              float* __restrict__ ssg) {
    const int mb = blockIdx.x, nb = blockIdx.y;
    const int t = threadIdx.x, l = t & 63, w = t >> 6;
    const int lr = l & 15, lc = l >> 4;
    const int rw = mb * 64 + w * 16;
    const int n0 = nb * 64;

    f32x4 acc[4];
#pragma unroll
    for (int ni = 0; ni < 4; ++ni) acc[ni] = (f32x4){0.f, 0.f, 0.f, 0.f};

#pragma unroll
    for (int kk = 0; kk < 8; ++kk) {
        const bf16x8 a = *(const bf16x8*)(Xb + (size_t)(rw + lr) * 256 + kk * 32 + lc * 8);
#pragma unroll
        for (int ni = 0; ni < 4; ++ni) {
            const bf16x8 b = *(const bf16x8*)(WB +
                ((size_t)((nb * 4 + ni) * 8 + kk) * 64 + l) * 8);
            acc[ni] = MFMA16(a, b, acc[ni]);
        }
    }

    if (nb == 20) {   // gates
        if (lr < 2) {
            const float bz = sb[1024 + lr];
            float* dst = lr ? ssg : sag;
#pragma unroll
            for (int v = 0; v < 4; ++v) {
                const float z = acc[0][v] + bz;
                dst[rw + lc * 4 + v] = 1.0f / (1.0f + expf(-z));
            }
        }
        return;
    }

    const int typ = nb >> 2;
    if (typ == 4) {   // base out (f32, no bias)
#pragma unroll
        for (int ni = 0; ni < 4; ++ni) {
            const int o = (n0 - 1024) + ni * 16 + lr;
#pragma unroll
            for (int v = 0; v < 4; ++v)
                out[(size_t)(rw + lc * 4 + v) * 256 + o] = acc[ni][v];
        }
        return;
    }

    if (typ == 0 || typ == 2) {   // A1 / S1 -> transposed [o][jb]
        bf16* dst = (typ == 0 ? A1T : S1T);
        const int ob = n0 - (typ == 0 ? 0 : 512);
#pragma unroll
        for (int ni = 0; ni < 4; ++ni) {
            const int o = ob + ni * 16 + lr;
            const float bz = sb[n0 + ni * 16 + lr];
            bf16x4 p;
#pragma unroll
            for (int v = 0; v < 4; ++v) p[v] = (bf16)(acc[ni][v] + bz);
            *(bf16x4*)(dst + (size_t)o * NTQ + rw + lc * 4) = p;
        }
    } else {                      // A2 / S2 -> row-major [jb][i] AND [i][jb]
        bf16* dstg = (typ == 1 ? A2g : S2g);
        bf16* dstt = (typ == 1 ? A2T : S2T);
        const int ib = n0 - (typ == 1 ? 256 : 768);
#pragma unroll
        for (int ni = 0; ni < 4; ++ni) {
            const int i = ib + ni * 16 + lr;
            const float bz = sb[n0 + ni * 16 + lr];
            bf16x4 p;
#pragma unroll
            for (int v = 0; v < 4; ++v) {
                const float fv = acc[ni][v] + bz;
                p[v] = (bf16)fv;
                dstg[(size_t)(rw + lc * 4 + v) * 256 + i] = (bf16)fv;
            }
            *(bf16x4*)(dstt + (size_t)i * NTQ + rw + lc * 4) = p;
        }
    }
}

// ---------------------------------------------------------------------------
// k_delta: per (c,b): delta[o][i], K=128(a)+128(s), gate fused into B operand.
// OPERAND-SWAPPED vs r8: A = A2T/S2T (M = i), B = gated A1T/S1T (N = o), so
// the C-layout gives 4 consecutive i per thread -> bf16x4 stores (was 2B x64).
// 1-deep B-side software pipeline; __launch_bounds__(512,4) -> 2 blocks/CU.
// ---------------------------------------------------------------------------
#define KD_LDA(K) {                                                         \
    const bf16* As_ = ((K) < 4) ? A2T : S2T;                                \
    const int jb_ = c * 128 + ((K) & 3) * 32 + lc * 8;                      \
    _Pragma("unroll")                                                       \
    for (int mi = 0; mi < 4; ++mi)                                          \
        aC[mi] = *(const bf16x8*)(As_ + (size_t)(i0 + mi * 16 + lr) * NTQ + jb_); }

#define KD_LDB(K, bv) {                                                     \
    const bf16* Bs_ = ((K) < 4) ? A1T : S1T;                                \
    const int jb_ = c * 128 + ((K) & 3) * 32 + lc * 8;                      \
    _Pragma("unroll")                                                       \
    for (int ni = 0; ni < 4; ++ni)                                          \
        bv[ni] = *(const bf16x8*)(Bs_ + (size_t)(o0 + ni * 16 + lr) * NTQ + jb_); }

#define KD_SC(K, bv) {                                                      \
    const float g_ = ((K) < 4) ? gA[(K) & 3] : gS[(K) & 3];                 \
    _Pragma("unroll")                                                       \
    for (int ni = 0; ni < 4; ++ni)                                          \
        _Pragma("unroll")                                                   \
        for (int e = 0; e < 8; ++e)                                         \
            bv[ni][e] = (bf16)(g_ * (float)bv[ni][e]); }

#define KD_MM(bv) {                                                         \
    _Pragma("unroll")                                                       \
    for (int ni = 0; ni < 4; ++ni)                                          \
        _Pragma("unroll")                                                   \
        for (int mi = 0; mi < 4; ++mi)                                      \
            acc[mi][ni] = MFMA16(aC[mi], bv[ni], acc[mi][ni]); }

__global__ __launch_bounds__(512, 4) void k_delta(const bf16* __restrict__ A1T,
                                                  const bf16* __restrict__ S1T,
                                                  const bf16* __restrict__ A2T,
                                                  const bf16* __restrict__ S2T,
                                                  const float* __restrict__ sag,
                                                  const float* __restrict__ ssg,
                                                  bf16* __restrict__ SPD) {
    const int bid = blockIdx.x;
    const int ih = bid & 1, bb = (bid >> 1) & 7, c = bid >> 4;
    const int t = threadIdx.x, l = t & 63, w = t >> 6;
    const int lr = l & 15, lc = l >> 4;
    const int i0 = ih * 128 + (w >> 2) * 64;
    const int o0 = (w & 3) * 64;

    // gates for this lane's k-slots: t_local = ka*4 + lc
    float gA[4], gS[4];
#pragma unroll
    for (int ta = 0; ta < 4; ++ta) {
        gA[ta] = sag[(c * 16 + ta * 4 + lc) * 8 + bb];
        gS[ta] = -ssg[(c * 16 + ta * 4 + lc) * 8 + bb];
    }

    f32x4 acc[4][4];
#pragma unroll
    for (int mi = 0; mi < 4; ++mi)
#pragma unroll
        for (int ni = 0; ni < 4; ++ni) acc[mi][ni] = (f32x4){0.f, 0.f, 0.f, 0.f};

    bf16x8 aC[4], bX[4], bY[4];

    KD_LDB(0, bX); KD_SC(0, bX);
    KD_LDA(0); KD_LDB(1, bY); KD_MM(bX); KD_SC(1, bY);
    KD_LDA(1); KD_LDB(2, bX); KD_MM(bY); KD_SC(2, bX);
    KD_LDA(2); KD_LDB(3, bY); KD_MM(bX); KD_SC(3, bY);
    KD_LDA(3); KD_LDB(4, bX); KD_MM(bY); KD_SC(4, bX);
    KD_LDA(4); KD_LDB(5, bY); KD_MM(bX); KD_SC(5, bY);
    KD_LDA(5); KD_LDB(6, bX); KD_MM(bY); KD_SC(6, bX);
    KD_LDA(6); KD_LDB(7, bY); KD_MM(bX); KD_SC(7, bY);
    KD_LDA(7); KD_MM(bY);

    // acc[mi][ni][v] = delta[o = o0+ni*16+lr][i = i0+mi*16+lc*4+v]
    bf16* dst = SPD + (size_t)((c * 8 + bb) * 256) * 256;
#pragma unroll
    for (int ni = 0; ni < 4; ++ni)
#pragma unroll
        for (int mi = 0; mi < 4; ++mi) {
            bf16x4 p;
#pragma unroll
            for (int v = 0; v < 4; ++v) p[v] = (bf16)(acc[mi][ni][v]);
            *(bf16x4*)(dst + (size_t)(o0 + ni * 16 + lr) * 256 + i0 + mi * 16 + lc * 4) = p;
        }
}

// ---------------------------------------------------------------------------
// k_prefix: in-place exclusive prefix over chunks; 4 groups of 8 batched loads
// so the serial chain exposes HBM/L2 latency 8x less often.
// ---------------------------------------------------------------------------
__global__ __launch_bounds__(256) void k_prefix(bf16* __restrict__ SPD) {
    const int idx = blockIdx.x * 256 + threadIdx.x;   // 65536 units
    const int ivv = idx & 31;
    const int o   = (idx >> 5) & 255;
    const int bb  = idx >> 13;
    bf16* p = SPD + ((size_t)(bb * 256 + o) * 256) + ivv * 8;
    float run[8];
#pragma unroll
    for (int e = 0; e < 8; ++e) run[e] = 0.f;
    for (int g = 0; g < 4; ++g) {
        bf16x8 d[8];
#pragma unroll
        for (int cc = 0; cc < 8; ++cc)
            d[cc] = *(const bf16x8*)(p + (size_t)(g * 8 + cc) * 524288);
#pragma unroll
        for (int cc = 0; cc < 8; ++cc) {
            bf16x8 s;
#pragma unroll
            for (int e = 0; e < 8; ++e) s[e] = (bf16)run[e];
            *(bf16x8*)(p + (size_t)(g * 8 + cc) * 524288) = s;
#pragma unroll
            for (int e = 0; e < 8; ++e) run[e] += (float)d[cc][e];
        }
    }
}

// ---------------------------------------------------------------------------
// k_out: fused inter (X @ state^T) + intra-chunk causal part.
// Block (c,b,oh) -> 512 blocks, 8 waves. Wave w: S-phase key-tile w (both
// parts) -> gate/mask -> PB; inter + out-phase on o-cols oh*128+w*16..+16.
// One barrier. Block owns its out rows/cols exclusively -> plain RMW.
// ---------------------------------------------------------------------------
__global__ __launch_bounds__(512, 4) void k_out(const bf16* __restrict__ Xb,
                                                const bf16* __restrict__ SPD,
                                                const bf16* __restrict__ A2g,
                                                const bf16* __restrict__ S2g,
                                                const bf16* __restrict__ A1T,
                                                const bf16* __restrict__ S1T,
                                                const float* __restrict__ sag,
                                                const float* __restrict__ ssg,
                                                float* __restrict__ out) {
    const int bid = blockIdx.x;
    const int oh = bid & 1, bb = (bid >> 1) & 7, c = bid >> 4;
    const int t = threadIdx.x, l = t & 63, w = t >> 6;
    const int lr = l & 15, lc = l >> 4;
    const int o0 = oh * 128 + w * 16;

    __shared__ __align__(16) bf16 PB[16][264];

    // X fragments: rows j=lr of (chunk c, batch bb)
    bf16x8 xa[8];
#pragma unroll
    for (int kk = 0; kk < 8; ++kk)
        xa[kk] = *(const bf16x8*)(Xb +
            (size_t)((c * 16 + lr) * 8 + bb) * 256 + kk * 32 + lc * 8);

    // ---- intra S phase: wave w owns key tile w (16 keys), a & s parts ----
    f32x4 sA = (f32x4){0.f, 0.f, 0.f, 0.f};
    f32x4 sS = (f32x4){0.f, 0.f, 0.f, 0.f};
#pragma unroll
    for (int kk = 0; kk < 8; ++kk) {
        const size_t roff = (size_t)(c * 128 + w * 16 + lr) * 256 + kk * 32 + lc * 8;
        sA = MFMA16(xa[kk], *(const bf16x8*)(A2g + roff), sA);
        sS = MFMA16(xa[kk], *(const bf16x8*)(S2g + roff), sS);
    }

    // gate + causal mask -> PB (row j, col = key local 0..255: a | s)
    {
        const int rl = w * 16 + lr;
        const int tl = rl >> 3;
        const float ga =  sag[(c * 16 + tl) * 8 + bb];
        const float gs = -ssg[(c * 16 + tl) * 8 + bb];
#pragma unroll
        for (int v = 0; v < 4; ++v) {
            const int j = lc * 4 + v;
            const bool m = (tl > j);
            PB[j][rl]       = (bf16)(m ? 0.f : ga * sA[v]);
            PB[j][128 + rl] = (bf16)(m ? 0.f : gs * sS[v]);
        }
    }

    // ---- inter part while PB settles: acco += X @ state[c,b]^T ----
    f32x4 acco = (f32x4){0.f, 0.f, 0.f, 0.f};
    const bf16* Sp = SPD + (size_t)((c * 8 + bb) * 256) * 256;
#pragma unroll
    for (int kk = 0; kk < 8; ++kk)
        acco = MFMA16(xa[kk],
                      *(const bf16x8*)(Sp + (size_t)(o0 + lr) * 256 + kk * 32 + lc * 8),
                      acco);

    __syncthreads();   // PB visible

    // ---- intra out phase: K' = 256 (a: A1T, s: S1T) ----
#pragma unroll
    for (int kk2 = 0; kk2 < 8; ++kk2) {
        const bf16* Tsrc = (kk2 < 4) ? A1T : S1T;
        const bf16x8 af = *(const bf16x8*)&PB[lr][kk2 * 32 + lc * 8];
        const bf16x8 b = *(const bf16x8*)(Tsrc + (size_t)(o0 + lr) * NTQ +
                                          c * 128 + (kk2 & 3) * 32 + lc * 8);
        acco = MFMA16(af, b, acco);
    }

    // ---- RMW into out (block-exclusive rows/cols) ----
#pragma unroll
    for (int v = 0; v < 4; ++v) {
        const size_t jb = (size_t)((c * 16 + lc * 4 + v) * 8 + bb);
        out[jb * 256 + o0 + lr] += acco[v];
    }
}

// ---------------------------------------------------------------------------
extern "C" void kernel_launch(void* const* d_in, const int* in_sizes, int n_in,
                              void* d_out, int out_size, void* d_ws, size_t ws_size,
                              hipStream_t stream) {
    const float* x  = (const float*)d_in[0];   // (512, 8, 256)
    const float* sw = (const float*)d_in[1];   // (1026, 256)
    const float* sb = (const float*)d_in[2];   // (1026,)
    const float* w0 = (const float*)d_in[3];   // (256, 256)
    float* out = (float*)d_out;                // (512, 8, 256)

    char* ws = (char*)d_ws;
    bf16*  WB  = (bf16*)(ws + 0);              // 688,128 B
    bf16*  Xb  = (bf16*)(ws + 688128);         // 2 MB
    bf16*  A1T = (bf16*)(ws + 2785280);        // 2 MB
    bf16*  S1T = (bf16*)(ws + 4882432);        // 2 MB
    bf16*  A2g = (bf16*)(ws + 6979584);        // 2 MB
    bf16*  S2g = (bf16*)(ws + 9076736);        // 2 MB
    bf16*  A2T = (bf16*)(ws + 11173888);       // 2 MB
    bf16*  S2T = (bf16*)(ws + 13271040);       // 2 MB
    float* sag = (float*)(ws + 15368192);      // 16 KB
    float* ssg = (float*)(ws + 15384576);      // 16 KB
    bf16*  SPD = (bf16*)(ws + 15400960);       // 32 MB (delta -> prefix states)

    k_init<<<1108, 256, 0, stream>>>(x, sw, w0, Xb, WB);
    dim3 gp(64, 21);
    k_prep<<<gp, 256, 0, stream>>>(Xb, WB, sb, A1T, S1T, A2g, S2g, A2T, S2T,
                                   out, sag, ssg);
    k_delta<<<512, 512, 0, stream>>>(A1T, S1T, A2T, S2T, sag, ssg, SPD);
    k_prefix<<<256, 256, 0, stream>>>(SPD);
    k_out<<<512, 512, 0, stream>>>(Xb, SPD, A2g, S2g, A1T, S1T, sag, ssg, out);
}

// Round 10
// 84.871 us; speedup vs baseline: 3.3111x; 1.1738x over previous
//
#include <hip/hip_runtime.h>
#include <math.h>

typedef __bf16 bf16;
typedef __attribute__((ext_vector_type(4))) __bf16 bf16x4;
typedef __attribute__((ext_vector_type(8))) __bf16 bf16x8;
typedef __attribute__((ext_vector_type(4))) float f32x4;

#define MFMA16(a, b, c) __builtin_amdgcn_mfma_f32_16x16x32_bf16(a, b, c, 0, 0, 0)
#define NCH 32      // chunks (16 j-steps each)

// Fragment-layout convention (16x16x32 MFMA, verified r6-r9):
//   operand frag: lane l -> row = tile*16 + (l&15), k = kk*32 + (l>>4)*8 + e(0..7)
//   C-frag: thread (lr=l&15, lc=l>>4) -> (firstArgRow = lc*4+v, secondArgRow = lr)
// All operand arrays are stored [tile-ish][64 lanes][8 e] so every wave load
// is one contiguous 1KB burst.

// ---------------------------------------------------------------------------
// k_init: bid<256: XF[jbtile][kk][l][8]  (x for k_prep A-operand)
//         bid<512: XO[c][bb][kk][l][8]   (x for k_out A-operand, rows j*8+bb)
//         else   : WB (k_prep B-operand, as r6-r9)
// ---------------------------------------------------------------------------
__global__ __launch_bounds__(256) void k_init(const float* __restrict__ x,
                                              const float* __restrict__ sw,
                                              const float* __restrict__ w0,
                                              bf16* __restrict__ XF,
                                              bf16* __restrict__ XO,
                                              bf16* __restrict__ WB) {
    const int bid = blockIdx.x;
    const int t = threadIdx.x, l = t & 63, kb = t >> 6;
    if (bid < 512) {
        const int col0 = (l >> 4) * 8;
#pragma unroll
        for (int pass = 0; pass < 2; ++pass) {
            const int kg = kb + pass * 4;
            size_t row;
            bf16* dst;
            if (bid < 256) {
                row = (size_t)(bid * 16 + (l & 15));
                dst = XF + ((size_t)(bid * 8 + kg) * 64 + l) * 8;
            } else {
                const int c = (bid - 256) >> 3, bb = (bid - 256) & 7;
                row = (size_t)((c * 16 + (l & 15)) * 8 + bb);
                dst = XO + ((size_t)(((c * 8 + bb) * 8) + kg) * 64 + l) * 8;
            }
            const float4 v0 = *(const float4*)(x + row * 256 + kg * 32 + col0);
            const float4 v1 = *(const float4*)(x + row * 256 + kg * 32 + col0 + 4);
            bf16x8 o;
            o[0] = (bf16)v0.x; o[1] = (bf16)v0.y; o[2] = (bf16)v0.z; o[3] = (bf16)v0.w;
            o[4] = (bf16)v1.x; o[5] = (bf16)v1.y; o[6] = (bf16)v1.z; o[7] = (bf16)v1.w;
            *(bf16x8*)dst = o;
        }
        return;
    }
    const int nb = bid - 512;                  // 0..83
    const int n = nb * 16 + (l & 15);
#pragma unroll
    for (int pass = 0; pass < 2; ++pass) {
        const int kk = kb + pass * 4;
        const int i0 = kk * 32 + (l >> 4) * 8;
        bf16x8 o;
        if (n < 1282) {
            const float* src = (n < 1024) ? (sw + (size_t)n * 256)
                             : (n < 1280) ? (w0 + (size_t)(n - 1024) * 256)
                                          : (sw + (size_t)(1024 + (n - 1280)) * 256);
#pragma unroll
            for (int e = 0; e < 8; ++e) o[e] = (bf16)src[i0 + e];
        } else {
#pragma unroll
            for (int e = 0; e < 8; ++e) o[e] = (bf16)0.0f;
        }
        *(bf16x8*)(WB + ((size_t)(nb * 8 + kk) * 64 + l) * 8) = o;
    }
}

// ---------------------------------------------------------------------------
// k_prep: MFMA GEMM C[4096 x 1282] = X @ W^T (+bias / sigmoid), epilogue
// writes every product in FRAGMENT layout:
//  nb 0..3  -> A1F[c][kkd][otile][l][8]   (rows o, k = jb within chunk)
//  nb 4..7  -> A2TF[c][kkd][itile][l][8]  (rows i, k = jb)  + A2GF[keytile][kkg][l][8] (rows jb, k = i)
//  nb 8..11 -> S1F ; 12..15 -> S2TF + S2GF ; 16..19 -> out base f32 ; 20 -> gates
// C-frag: (jb = rw + lc*4+v, n = n0 + ni*16 + lr).
// A1F mapping: c=mb>>1, kkd=((mb&1)<<1)|(w>>1), lcD=((w&1)<<1)|(lc>>1),
//              laneD=lr+16*lcD, e=(lc&1)*4+v  -> 512B-contiguous wave stores.
// ---------------------------------------------------------------------------
__global__ __launch_bounds__(256) void k_prep(const bf16* __restrict__ XF,
                                              const bf16* __restrict__ WB,
                                              const float* __restrict__ sb,
                                              bf16* __restrict__ A1F,
                                              bf16* __restrict__ S1F,
                                              bf16* __restrict__ A2TF,
                                              bf16* __restrict__ S2TF,
                                              bf16* __restrict__ A2GF,
                                              bf16* __restrict__ S2GF,
                                              float* __restrict__ out,
                                              float* __restrict__ sag,
                                              float* __restrict__ ssg) {
    const int mb = blockIdx.x, nb = blockIdx.y;
    const int t = threadIdx.x, l = t & 63, w = t >> 6;
    const int lr = l & 15, lc = l >> 4;
    const int rw = mb * 64 + w * 16;
    const int n0 = nb * 64;

    f32x4 acc[4];
#pragma unroll
    for (int ni = 0; ni < 4; ++ni) acc[ni] = (f32x4){0.f, 0.f, 0.f, 0.f};

#pragma unroll
    for (int kk = 0; kk < 8; ++kk) {
        const bf16x8 a = *(const bf16x8*)(XF + ((size_t)((mb * 4 + w) * 8 + kk) * 64 + l) * 8);
#pragma unroll
        for (int ni = 0; ni < 4; ++ni) {
            const bf16x8 b = *(const bf16x8*)(WB +
                ((size_t)((nb * 4 + ni) * 8 + kk) * 64 + l) * 8);
            acc[ni] = MFMA16(a, b, acc[ni]);
        }
    }

    if (nb == 20) {   // gates
        if (lr < 2) {
            const float bz = sb[1024 + lr];
            float* dst = lr ? ssg : sag;
#pragma unroll
            for (int v = 0; v < 4; ++v) {
                const float z = acc[0][v] + bz;
                dst[rw + lc * 4 + v] = 1.0f / (1.0f + expf(-z));
            }
        }
        return;
    }

    const int typ = nb >> 2;
    if (typ == 4) {   // base out (f32, no bias)
#pragma unroll
        for (int ni = 0; ni < 4; ++ni) {
            const int o = (n0 - 1024) + ni * 16 + lr;
#pragma unroll
            for (int v = 0; v < 4; ++v)
                out[(size_t)(rw + lc * 4 + v) * 256 + o] = acc[ni][v];
        }
        return;
    }

    const int c   = mb >> 1;
    const int kkd = ((mb & 1) << 1) | (w >> 1);
    const int lcD = ((w & 1) << 1) | (lc >> 1);
    const int laneD = lr + 16 * lcD;
    const int eoff  = (lc & 1) * 4;

    if (typ == 0 || typ == 2) {   // A1F / S1F
        bf16* dst = (typ == 0 ? A1F : S1F);
        const int tb = (typ == 0 ? nb : nb - 8) * 4;
#pragma unroll
        for (int ni = 0; ni < 4; ++ni) {
            const float bz = sb[n0 + ni * 16 + lr];
            bf16x4 p;
#pragma unroll
            for (int v = 0; v < 4; ++v) p[v] = (bf16)(acc[ni][v] + bz);
            *(bf16x4*)(dst + ((size_t)((c * 4 + kkd) * 16 + tb + ni) * 64 + laneD) * 8 + eoff) = p;
        }
    } else {                      // A2TF/S2TF + A2GF/S2GF
        bf16* dstT = (typ == 1 ? A2TF : S2TF);
        bf16* dstG = (typ == 1 ? A2GF : S2GF);
        const int nbr = (typ == 1 ? nb - 4 : nb - 12);
        const int keytile = mb * 4 + w;
#pragma unroll
        for (int ni = 0; ni < 4; ++ni) {
            const float bz = sb[n0 + ni * 16 + lr];
            bf16x4 p;
#pragma unroll
            for (int v = 0; v < 4; ++v) p[v] = (bf16)(acc[ni][v] + bz);
            *(bf16x4*)(dstT + ((size_t)((c * 4 + kkd) * 16 + nbr * 4 + ni) * 64 + laneD) * 8 + eoff) = p;
            // A2GF: rows = jb, k = i.  i = nbr*64 + ni*16 + lr (fixed per thread)
            const int kkg = nbr * 2 + (ni >> 1);
            const int lcG = ((ni & 1) << 1) | (lr >> 3);
            const int eG  = lr & 7;
#pragma unroll
            for (int v = 0; v < 4; ++v)
                dstG[((size_t)(keytile * 8 + kkg) * 64 + (lc * 4 + v) + 16 * lcG) * 8 + eG] = p[v];
        }
    }
}

// ---------------------------------------------------------------------------
// k_delta: per (c,b,ih): delta[o][i] for i-half ih. All operand loads are
// contiguous 1KB fragment bursts; gate fused into B (per-k-element scalar);
// stores DIRECTLY into SPDF fragment layout (512B-contiguous wave stores).
// SPDF[c][bb][kk(8)][otile(16)][l(64)][e(8)]: row o = otile*16+(l&15),
//   i = kk*32 + (l>>4)*8 + e.
// ---------------------------------------------------------------------------
#define KD_LDA(K) {                                                          \
    const bf16* As_ = ((K) < 4) ? A2TF : S2TF;                               \
    _Pragma("unroll")                                                        \
    for (int mi = 0; mi < 4; ++mi)                                           \
        aC[mi] = *(const bf16x8*)(As_ +                                      \
            ((size_t)((c * 4 + ((K) & 3)) * 16 + itile0 + mi) * 64 + l) * 8); }

#define KD_LDB(K, bv) {                                                      \
    const bf16* Bs_ = ((K) < 4) ? A1F : S1F;                                 \
    _Pragma("unroll")                                                        \
    for (int ni = 0; ni < 4; ++ni)                                           \
        bv[ni] = *(const bf16x8*)(Bs_ +                                      \
            ((size_t)((c * 4 + ((K) & 3)) * 16 + otile0 + ni) * 64 + l) * 8); }

#define KD_SC(K, bv) {                                                       \
    const float g_ = ((K) < 4) ? gA[(K) & 3] : gS[(K) & 3];                  \
    _Pragma("unroll")                                                        \
    for (int ni = 0; ni < 4; ++ni)                                           \
        _Pragma("unroll")                                                    \
        for (int e = 0; e < 8; ++e)                                          \
            bv[ni][e] = (bf16)(g_ * (float)bv[ni][e]); }

#define KD_MM(bv) {                                                          \
    _Pragma("unroll")                                                        \
    for (int ni = 0; ni < 4; ++ni)                                           \
        _Pragma("unroll")                                                    \
        for (int mi = 0; mi < 4; ++mi)                                       \
            acc[mi][ni] = MFMA16(aC[mi], bv[ni], acc[mi][ni]); }

__global__ __launch_bounds__(512, 4) void k_delta(const bf16* __restrict__ A1F,
                                                  const bf16* __restrict__ S1F,
                                                  const bf16* __restrict__ A2TF,
                                                  const bf16* __restrict__ S2TF,
                                                  const float* __restrict__ sag,
                                                  const float* __restrict__ ssg,
                                                  bf16* __restrict__ SPD) {
    const int bid = blockIdx.x;
    const int ih = bid & 1, bb = (bid >> 1) & 7, c = bid >> 4;
    const int t = threadIdx.x, l = t & 63, w = t >> 6;
    const int lr = l & 15, lc = l >> 4;
    const int itile0 = ih * 8 + (w >> 2) * 4;   // i = itile*16 + row
    const int otile0 = (w & 3) * 4;             // o = otile*16 + row

    // gate per k-slot: t_local = ka*4 + lc  (8 consecutive jb = one step)
    float gA[4], gS[4];
#pragma unroll
    for (int ta = 0; ta < 4; ++ta) {
        gA[ta] = sag[(c * 16 + ta * 4 + lc) * 8 + bb];
        gS[ta] = -ssg[(c * 16 + ta * 4 + lc) * 8 + bb];
    }

    f32x4 acc[4][4];
#pragma unroll
    for (int mi = 0; mi < 4; ++mi)
#pragma unroll
        for (int ni = 0; ni < 4; ++ni) acc[mi][ni] = (f32x4){0.f, 0.f, 0.f, 0.f};

    bf16x8 aC[4], bX[4], bY[4];

    KD_LDB(0, bX); KD_SC(0, bX);
    KD_LDA(0); KD_LDB(1, bY); KD_MM(bX); KD_SC(1, bY);
    KD_LDA(1); KD_LDB(2, bX); KD_MM(bY); KD_SC(2, bX);
    KD_LDA(2); KD_LDB(3, bY); KD_MM(bX); KD_SC(3, bY);
    KD_LDA(3); KD_LDB(4, bX); KD_MM(bY); KD_SC(4, bX);
    KD_LDA(4); KD_LDB(5, bY); KD_MM(bX); KD_SC(5, bY);
    KD_LDA(5); KD_LDB(6, bX); KD_MM(bY); KD_SC(6, bX);
    KD_LDA(6); KD_LDB(7, bY); KD_MM(bX); KD_SC(7, bY);
    KD_LDA(7); KD_MM(bY);

    // acc[mi][ni][v] = delta[o = otile0*16+ni*16+lr][i = (itile0+mi)*16+lc*4+v]
    // SPDF store: kkD = i>>5 = ih*4+(w>>2)*2+(mi>>1); lcDD = ((mi&1)<<1)|(lc>>1)
    const size_t base = (size_t)(c * 8 + bb) * 8;
#pragma unroll
    for (int mi = 0; mi < 4; ++mi) {
        const int kkD  = ih * 4 + (w >> 2) * 2 + (mi >> 1);
        const int slot = lr + 16 * (((mi & 1) << 1) | (lc >> 1));
        const int eoff = (lc & 1) * 4;
#pragma unroll
        for (int ni = 0; ni < 4; ++ni) {
            bf16x4 p;
#pragma unroll
            for (int v = 0; v < 4; ++v) p[v] = (bf16)(acc[mi][ni][v]);
            *(bf16x4*)(SPD + ((base + kkD) * 16 + otile0 + ni) * 512 + slot * 8 + eoff) = p;
        }
    }
}

// ---------------------------------------------------------------------------
// k_prefix: in-place exclusive prefix over chunks in SPDF layout.
// Thread owns (bb,otile,kk,sl): one contiguous bf16x8 per chunk. Fully
// coalesced (64 consecutive threads = 1KB). Batched 8 to hide latency.
// ---------------------------------------------------------------------------
__global__ __launch_bounds__(256) void k_prefix(bf16* __restrict__ SPD) {
    const int idx = blockIdx.x * 256 + threadIdx.x;   // 65536
    const int sl    = idx & 63;
    const int kk    = (idx >> 6) & 7;
    const int otile = (idx >> 9) & 15;
    const int bb    = idx >> 13;
    bf16* p = SPD + ((size_t)((bb * 8 + kk) * 16 + otile)) * 512 + sl * 8;
    float run[8];
#pragma unroll
    for (int e = 0; e < 8; ++e) run[e] = 0.f;
    for (int g = 0; g < 4; ++g) {
        bf16x8 d[8];
#pragma unroll
        for (int cc = 0; cc < 8; ++cc)
            d[cc] = *(const bf16x8*)(p + (size_t)(g * 8 + cc) * 524288);
#pragma unroll
        for (int cc = 0; cc < 8; ++cc) {
            bf16x8 s;
#pragma unroll
            for (int e = 0; e < 8; ++e) s[e] = (bf16)run[e];
            *(bf16x8*)(p + (size_t)(g * 8 + cc) * 524288) = s;
#pragma unroll
            for (int e = 0; e < 8; ++e) run[e] += (float)d[cc][e];
        }
    }
}

// ---------------------------------------------------------------------------
// k_out: fused inter (X @ state^T) + intra-chunk causal. Block (c,bb,oh),
// 8 waves. All operand loads contiguous fragment bursts.
// S^T phase: MFMA(A2GF(keys), XO(j)) -> C (key = lc*4+v, j = lr); gate+mask
// -> PB[j][key] (bf16x4 LDS stores). One barrier. Then inter MFMA(XO, SPDF)
// + intra MFMA(PB(j-rows), A1F/S1F(o-rows)), both into acco; single RMW.
// ---------------------------------------------------------------------------
__global__ __launch_bounds__(512, 4) void k_out(const bf16* __restrict__ XO,
                                                const bf16* __restrict__ SPD,
                                                const bf16* __restrict__ A2GF,
                                                const bf16* __restrict__ S2GF,
                                                const bf16* __restrict__ A1F,
                                                const bf16* __restrict__ S1F,
                                                const float* __restrict__ sag,
                                                const float* __restrict__ ssg,
                                                float* __restrict__ out) {
    const int bid = blockIdx.x;
    const int oh = bid & 1, bb = (bid >> 1) & 7, c = bid >> 4;
    const int t = threadIdx.x, l = t & 63, w = t >> 6;
    const int lr = l & 15, lc = l >> 4;

    __shared__ __align__(16) bf16 PB[16][264];

    // X fragments (rows j = l&15 of chunk c, batch bb)
    bf16x8 xa[8];
#pragma unroll
    for (int kk = 0; kk < 8; ++kk)
        xa[kk] = *(const bf16x8*)(XO + ((size_t)((c * 8 + bb) * 8 + kk) * 64 + l) * 8);

    // ---- S^T phase: wave w owns key tile (c*8+w), both parts ----
    f32x4 sA = (f32x4){0.f, 0.f, 0.f, 0.f};
    f32x4 sS = (f32x4){0.f, 0.f, 0.f, 0.f};
#pragma unroll
    for (int kk = 0; kk < 8; ++kk) {
        const size_t ko = ((size_t)((c * 8 + w) * 8 + kk) * 64 + l) * 8;
        sA = MFMA16(*(const bf16x8*)(A2GF + ko), xa[kk], sA);
        sS = MFMA16(*(const bf16x8*)(S2GF + ko), xa[kk], sS);
    }

    // gate + causal mask -> PB.  key local = w*16 + lc*4 + v; step tl = w*2+(lc>>1)
    {
        const int tl = w * 2 + (lc >> 1);
        const float ga =  sag[(c * 16 + tl) * 8 + bb];
        const float gs = -ssg[(c * 16 + tl) * 8 + bb];
        const bool m = (tl > lr);   // j = lr
        bf16x4 pa, ps;
#pragma unroll
        for (int v = 0; v < 4; ++v) {
            pa[v] = (bf16)(m ? 0.f : ga * sA[v]);
            ps[v] = (bf16)(m ? 0.f : gs * sS[v]);
        }
        *(bf16x4*)&PB[lr][w * 16 + lc * 4]       = pa;
        *(bf16x4*)&PB[lr][128 + w * 16 + lc * 4] = ps;
    }

    // ---- inter part while PB settles: acco += X @ state^T ----
    f32x4 acco = (f32x4){0.f, 0.f, 0.f, 0.f};
#pragma unroll
    for (int kk = 0; kk < 8; ++kk) {
        const bf16x8 b = *(const bf16x8*)(SPD +
            ((size_t)(((c * 8 + bb) * 8 + kk) * 16 + oh * 8 + w) * 64 + l) * 8);
        acco = MFMA16(xa[kk], b, acco);
    }

    __syncthreads();   // PB visible

    // ---- intra out phase: K' = 256 (a: A1F, s: S1F), o-tile = oh*8+w ----
#pragma unroll
    for (int kk2 = 0; kk2 < 8; ++kk2) {
        const bf16* Tsrc = (kk2 < 4) ? A1F : S1F;
        const bf16x8 af = *(const bf16x8*)&PB[lr][(kk2 >> 2) * 128 + (kk2 & 3) * 32 + lc * 8];
        const bf16x8 b = *(const bf16x8*)(Tsrc +
            ((size_t)((c * 4 + (kk2 & 3)) * 16 + oh * 8 + w) * 64 + l) * 8);
        acco = MFMA16(af, b, acco);
    }

    // ---- RMW into out (block-exclusive rows/cols) ----
#pragma unroll
    for (int v = 0; v < 4; ++v) {
        const size_t jb = (size_t)((c * 16 + lc * 4 + v) * 8 + bb);
        out[jb * 256 + oh * 128 + w * 16 + lr] += acco[v];
    }
}

// ---------------------------------------------------------------------------
extern "C" void kernel_launch(void* const* d_in, const int* in_sizes, int n_in,
                              void* d_out, int out_size, void* d_ws, size_t ws_size,
                              hipStream_t stream) {
    const float* x  = (const float*)d_in[0];   // (512, 8, 256)
    const float* sw = (const float*)d_in[1];   // (1026, 256)
    const float* sb = (const float*)d_in[2];   // (1026,)
    const float* w0 = (const float*)d_in[3];   // (256, 256)
    float* out = (float*)d_out;                // (512, 8, 256)

    char* ws = (char*)d_ws;
    bf16*  WB   = (bf16*)(ws + 0);             // 688,128 B
    bf16*  XF   = (bf16*)(ws + 688128);        // 2 MB
    bf16*  XO   = (bf16*)(ws + 2785280);       // 2 MB
    bf16*  A1F  = (bf16*)(ws + 4882432);       // 2 MB
    bf16*  S1F  = (bf16*)(ws + 6979584);       // 2 MB
    bf16*  A2TF = (bf16*)(ws + 9076736);       // 2 MB
    bf16*  S2TF = (bf16*)(ws + 11173888);      // 2 MB
    bf16*  A2GF = (bf16*)(ws + 13271040);      // 2 MB
    bf16*  S2GF = (bf16*)(ws + 15368192);      // 2 MB
    float* sag  = (float*)(ws + 17465344);     // 16 KB
    float* ssg  = (float*)(ws + 17481728);     // 16 KB
    bf16*  SPD  = (bf16*)(ws + 17498112);      // 32 MB (deltas -> prefix states)

    k_init<<<596, 256, 0, stream>>>(x, sw, w0, XF, XO, WB);
    dim3 gp(64, 21);
    k_prep<<<gp, 256, 0, stream>>>(XF, WB, sb, A1F, S1F, A2TF, S2TF, A2GF, S2GF,
                                   out, sag, ssg);
    k_delta<<<512, 512, 0, stream>>>(A1F, S1F, A2TF, S2TF, sag, ssg, SPD);
    k_prefix<<<256, 256, 0, stream>>>(SPD);
    k_out<<<512, 512, 0, stream>>>(XO, SPD, A2GF, S2GF, A1F, S1F, sag, ssg, out);
}